// Round 7
// baseline (19561.205 us; speedup 1.0000x reference)
//
#include <hip/hip_runtime.h>
#include <hip/hip_bf16.h>

__device__ __forceinline__ float ldx(const void* p, int i, bool f32) {
    return f32 ? ((const float*)p)[i] : (float)(((const __bf16*)p)[i]);
}

// Width-aware int read: if the array is int64 (little-endian), element i's low
// word sits at int32 index 2*i. Values here all fit in 32 bits (0..29).
__device__ __forceinline__ int geti(const int* p, int i, bool i64) {
    return p[i64 ? 2 * i : i];
}

// Literal reference transcription. 256 thr = 4 waves; each wave owns 2 batch
// rows; 8 rows/block. Uniform control flow -> __syncthreads legal everywhere.
// OUTPUT IS FLOAT32 (reference returns jnp.float32; harness types d_out by the
// reference's OUTPUT dtype even though inputs were bf16-converted).
__global__ __launch_bounds__(256, 2) void gn_ref(
    const void* obs, const void* act, const void* ag, const void* g,
    const void* mp_w, const void* mp_b,
    const void* w1, const void* b1, const void* w2, const void* b2,
    const void* w3, const void* b3, const void* w4, const void* b4,
    const void* rw1, const void* rb1, const void* rw2, const void* rb2,
    const int* eA, const int* eB, const int* pred_ids, const int* incoming,
    float* out, int Btot)
{
    __shared__ float s_row[8 * 120];      // [obs85 | act4 | dg30 | pad]
    __shared__ float s_agg[8 * 5 * 128];
    __shared__ float s_h[8 * 256];
    __shared__ int s_esrc[20], s_edst[20], s_p0[20], s_p1[20], s_inc[20], s_f[2];

    int tid = threadIdx.x, lane = tid & 63, w = tid >> 6;

    // ---- float dtype detection (fp32 misread as bf16 -> exponent 0xFF) ----
    if (tid == 0) { s_f[0] = 0; s_f[1] = 0; }
    __syncthreads();
    {
        const unsigned short* uo = (const unsigned short*)obs;
        const unsigned short* uw = (const unsigned short*)w2;
        int bad = 0;
        for (int i = tid; i < 8192; i += 256)
            if (((uo[i] >> 7) & 0xFF) == 0xFF) bad = 1;
        if (bad) atomicOr(&s_f[0], 1);
        bad = 0;
        for (int i = tid; i < 8192; i += 256)
            if (((uw[i] >> 7) & 0xFF) == 0xFF) bad = 1;
        if (bad) atomicOr(&s_f[1], 1);
    }

    // ---- int width detection (int64 marshaling makes these probes read 0) ----
    bool i64_i = (incoming[1] == 0);
    bool i64_p = (pred_ids[1] == 0);
    bool i64_e = (eA[9] == 0);

    // ---- src/dst disambiguation by content: edges_src[4] == 1 (dst[4]==0) ----
    const int* es;
    const int* ed;
    if (geti(eA, 4, i64_e) == 1) { es = eA; ed = eB; }
    else                         { es = eB; ed = eA; }

    if (tid < 20) {
        s_esrc[tid] = geti(es, tid, i64_e);
        s_edst[tid] = geti(ed, tid, i64_e);
        s_p0[tid] = geti(pred_ids, 2 * tid, i64_p);
        s_p1[tid] = geti(pred_ids, 2 * tid + 1, i64_p);
        s_inc[tid] = geti(incoming, tid, i64_i);
    }
    __syncthreads();
    bool fI = s_f[0] != 0, fW = s_f[1] != 0;

    // ---- stage rows ----
    int b0 = blockIdx.x * 8;
    for (int i = tid; i < 8 * 120; i += 256) {
        int rr = i / 120, c = i % 120;
        int bg = b0 + rr;
        float v = 0.f;
        if (bg < Btot) {
            if (c < 85) v = ldx(obs, bg * 85 + c, fI);
            else if (c < 89) v = ldx(act, bg * 4 + (c - 85), fI);
            else if (c < 119) {
                int t = c - 89;
                v = ldx(g, bg * 30 + t, fI) - ldx(ag, bg * 30 + t, fI);
            }
        }
        s_row[i] = v;
    }
    __syncthreads();

    // ---- edge MLP + aggregation: agg[o] = sum_j feat[incoming[o][j]] ----
    for (int rr = 0; rr < 2; ++rr) {
        int lr = w * 2 + rr;
        const float* row = s_row + lr * 120;
        float aggl[5], aggh[5];
#pragma unroll
        for (int o = 0; o < 5; ++o) { aggl[o] = 0.f; aggh[o] = 0.f; }
        for (int o = 0; o < 5; ++o)
            for (int j = 0; j < 4; ++j) {
                int e = s_inc[o * 4 + j];
                int so = s_esrc[e], dn = s_edst[e], p0 = s_p0[e], p1 = s_p1[e];
                float al = 0.f, ah = 0.f;
                for (int k = 0; k < 46; ++k) {
                    float x;
                    if (k < 10) x = row[k];                             // obs_body
                    else if (k < 14) x = row[85 + (k - 10)];            // act
                    else if (k == 14) x = row[89 + p0];                 // dg_sel[0]
                    else if (k == 15) x = row[89 + p1];                 // dg_sel[1]
                    else if (k < 31) x = row[10 + so * 15 + (k - 16)];  // src obj
                    else x = row[10 + dn * 15 + (k - 31)];              // dst obj
                    al += x * ldx(mp_w, k * 128 + lane, fW);
                    ah += x * ldx(mp_w, k * 128 + 64 + lane, fW);
                }
                al += ldx(mp_b, lane, fW);
                ah += ldx(mp_b, 64 + lane, fW);
                aggl[o] += fmaxf(al, 0.f);
                aggh[o] += fmaxf(ah, 0.f);
            }
#pragma unroll
        for (int o = 0; o < 5; ++o) {
            s_agg[(lr * 5 + o) * 128 + lane] = aggl[o];
            s_agg[(lr * 5 + o) * 128 + 64 + lane] = aggh[o];
        }
    }
    __syncthreads();

    // ---- twin phi MLPs + rho (uniform loops; barriers around s_h reuse) ----
    float qacc[2][2];  // [rr][tw]
    qacc[0][0] = qacc[0][1] = qacc[1][0] = qacc[1][1] = 0.f;
    for (int o = 0; o < 5; ++o) {
        for (int tw = 0; tw < 2; ++tw) {
            const void* Wa = tw ? w3 : w1;
            const void* Ba = tw ? b3 : b1;
            const void* Wb = tw ? w4 : w2;
            const void* Bb = tw ? b4 : b2;
            const void* Rh = tw ? rw2 : rw1;
            for (int rr = 0; rr < 2; ++rr) {
                int lr = w * 2 + rr;
                const float* row = s_row + lr * 120;
                const float* agp = s_agg + (lr * 5 + o) * 128;
                float hv[4];
#pragma unroll
                for (int nn = 0; nn < 4; ++nn) {
                    int n = nn * 64 + lane;
                    float z = 0.f;
                    // inp = [act(4), body(10), obj(15), agg(128)] matching w1 rows
                    for (int k = 0; k < 4; ++k) z += row[85 + k] * ldx(Wa, k * 256 + n, fW);
                    for (int k = 0; k < 10; ++k) z += row[k] * ldx(Wa, (4 + k) * 256 + n, fW);
                    for (int k = 0; k < 15; ++k)
                        z += row[10 + o * 15 + k] * ldx(Wa, (14 + k) * 256 + n, fW);
                    for (int k = 0; k < 128; ++k)
                        z += agp[k] * ldx(Wa, (29 + k) * 256 + n, fW);
                    hv[nn] = fmaxf(z + ldx(Ba, n, fW), 0.f);
                }
                __syncthreads();  // previous iteration's s_h reads complete
#pragma unroll
                for (int nn = 0; nn < 4; ++nn) s_h[lr * 256 + nn * 64 + lane] = hv[nn];
                __syncthreads();  // writes visible
#pragma unroll
                for (int nn = 0; nn < 4; ++nn) {
                    int n = nn * 64 + lane;
                    float z = 0.f;
                    for (int k = 0; k < 256; ++k)
                        z += s_h[lr * 256 + k] * ldx(Wb, k * 256 + n, fW);
                    qacc[rr][tw] += fmaxf(z + ldx(Bb, n, fW), 0.f) * ldx(Rh, n, fW);
                }
            }
        }
    }

    // ---- reduce over 64 lanes and write (FLOAT32 output) ----
    for (int rr = 0; rr < 2; ++rr) {
        int bg = b0 + w * 2 + rr;
        float q0 = qacc[rr][0], q1 = qacc[rr][1];
#pragma unroll
        for (int mask = 1; mask < 64; mask <<= 1) {
            q0 += __shfl_xor(q0, mask);
            q1 += __shfl_xor(q1, mask);
        }
        if (lane == 0 && bg < Btot) {
            out[bg] = q0 + ldx(rb1, 0, fW);
            out[Btot + bg] = q1 + ldx(rb2, 0, fW);
        }
    }
}

extern "C" void kernel_launch(void* const* d_in, const int* in_sizes, int n_in,
                              void* d_out, int out_size, void* d_ws, size_t ws_size,
                              hipStream_t stream) {
    (void)d_ws; (void)ws_size;
    int B = out_size / 2;  // 16384

    // ---- order-robust input resolution by size signature ----
    const void *obs = nullptr, *act = nullptr, *ag = nullptr, *g = nullptr;
    const void *mp_w = nullptr, *mp_b = nullptr;
    const void *w1 = nullptr, *b1 = nullptr, *w2 = nullptr, *b2 = nullptr;
    const void *w3 = nullptr, *b3 = nullptr, *w4 = nullptr, *b4 = nullptr;
    const void *rw1 = nullptr, *rb1 = nullptr, *rw2 = nullptr, *rb2 = nullptr;
    const int *eA = nullptr, *eB = nullptr, *pred = nullptr, *inc = nullptr;
    int c30 = 0, c256 = 0, c1 = 0, c40k = 0, c65k = 0, c20 = 0;
    for (int i = 0; i < n_in; ++i) {
        int sz = in_sizes[i];
        const void* p = d_in[i];
        if (sz == B * 85) obs = p;
        else if (sz == B * 30) { if (c30++ == 0) ag = p; else g = p; }
        else if (sz == 5888) mp_w = p;
        else if (sz == 128) mp_b = p;
        else if (sz == 40192) { if (c40k++ == 0) w1 = p; else w3 = p; }
        else if (sz == 65536 || sz == B * 4) {
            // act(B*4), phi_w2, phi_w4 collide at 65536 when B=16384; relative
            // order is act, w2, w4 under both dict and alphabetical orders.
            int c = c65k++;
            if (c == 0) act = p; else if (c == 1) w2 = p; else w4 = p;
        }
        else if (sz == 256) {
            int c = c256++;
            if (c == 0) b1 = p; else if (c == 1) b2 = p; else if (c == 2) b3 = p;
            else if (c == 3) b4 = p; else if (c == 4) rw1 = p; else rw2 = p;
        }
        else if (sz == 1) { if (c1++ == 0) rb1 = p; else rb2 = p; }
        else if (sz == 40) pred = (const int*)p;
        else if (sz == 20) {
            int c = c20++;
            if (c == 0) eA = (const int*)p;
            else if (c == 1) eB = (const int*)p;
            else inc = (const int*)p;
        }
    }
    if (!obs || !act || !ag || !g || !mp_w || !mp_b || !w1 || !b1 || !w2 || !b2 ||
        !w3 || !b3 || !w4 || !b4 || !rw1 || !rb1 || !rw2 || !rb2 || !eA || !eB ||
        !pred || !inc) {
        obs = d_in[0]; act = d_in[1]; ag = d_in[2]; g = d_in[3];
        mp_w = d_in[4]; mp_b = d_in[5]; w1 = d_in[6]; b1 = d_in[7];
        w2 = d_in[8]; b2 = d_in[9]; w3 = d_in[10]; b3 = d_in[11];
        w4 = d_in[12]; b4 = d_in[13]; rw1 = d_in[14]; rb1 = d_in[15];
        rw2 = d_in[16]; rb2 = d_in[17];
        eA = (const int*)d_in[18]; eB = (const int*)d_in[19];
        pred = (const int*)d_in[20]; inc = (const int*)d_in[21];
    }

    float* out = (float*)d_out;
    int grid = (B + 7) / 8;
    gn_ref<<<grid, 256, 0, stream>>>(obs, act, ag, g, mp_w, mp_b, w1, b1, w2, b2,
                                     w3, b3, w4, b4, rw1, rb1, rw2, rb2,
                                     eA, eB, pred, inc,
                                     out, B);
}

// Round 8
// 243.591 us; speedup vs baseline: 80.3034x; 80.3034x over previous
//
#include <hip/hip_runtime.h>
#include <hip/hip_bf16.h>

typedef __bf16 bf16x8 __attribute__((ext_vector_type(8)));
typedef float f32x4 __attribute__((ext_vector_type(4)));

#define MFMA(a, b, c) __builtin_amdgcn_mfma_f32_16x16x32_bf16(a, b, c, 0, 0, 0)

// ws layout (bf16 element offsets) — all weights in MFMA B-fragment order:
// frag[(nt*nKT + kt)*64 + lane][j] = W[kt*32 + (lane>>4)*8 + j][nt*16 + (lane&15)]
constexpr int MP_OFF = 0;        // mp_w:  K46->64,  N128: 8 nt * 2 kt * 512 = 8192
constexpr int W1_OFF = 8192;     // phi_w1: K157->160 (reordered), N256: 16*5*512 = 40960
constexpr int W2_OFF = 49152;    // phi_w2: K256, N256: 16*8*512 = 65536
constexpr int W3_OFF = 114688;
constexpr int W4_OFF = 155648;
constexpr int WS_TOTAL = 221184;                   // bf16 elems
constexpr size_t WS_BYTES = (size_t)WS_TOTAL * 2;  // 442368 bytes

__device__ __forceinline__ float ldf(const void* p, int i, bool f32) {
    return f32 ? ((const float*)p)[i] : (float)(((const __bf16*)p)[i]);
}
__device__ __forceinline__ int geti(const int* p, int i, bool i64) {
    return p[i64 ? 2 * i : i];
}

// ---- weight swizzle into B-fragment order (runs every launch) -------------
__global__ void swz(const void* __restrict__ mp, const void* __restrict__ w1,
                    const void* __restrict__ w2, const void* __restrict__ w3,
                    const void* __restrict__ w4, __bf16* __restrict__ ws) {
    __shared__ int s_f;
    if (threadIdx.x == 0) s_f = 0;
    __syncthreads();
    {
        const unsigned short* uw = (const unsigned short*)w2;
        int bad = 0;
        for (int i = threadIdx.x; i < 8192; i += 256)
            if (((uw[i] >> 7) & 0xFF) == 0xFF) bad = 1;
        if (bad) atomicOr(&s_f, 1);
    }
    __syncthreads();
    bool f32 = s_f != 0;

    int idx = blockIdx.x * blockDim.x + threadIdx.x;
    if (idx >= WS_TOTAL) return;
    const void* src;
    int local, nKT, N, style;
    if (idx < W1_OFF)      { src = mp; local = idx;          nKT = 2; N = 128; style = 0; }
    else if (idx < W2_OFF) { src = w1; local = idx - W1_OFF; nKT = 5; N = 256; style = 1; }
    else if (idx < W3_OFF) { src = w2; local = idx - W2_OFF; nKT = 8; N = 256; style = 0; }
    else if (idx < W4_OFF) { src = w3; local = idx - W4_OFF < 0 ? idx - W3_OFF : idx - W3_OFF, local = idx - W3_OFF, nKT = 5, N = 256, style = 1; }
    else                   { src = w4; local = idx - W4_OFF; nKT = 8; N = 256; style = 0; }
    int j = local & 7, lane = (local >> 3) & 63, t = local >> 9;
    int kt = t % nKT, nt = t / nKT;
    int k = kt * 32 + ((lane >> 4) << 3) + j;
    int n = nt * 16 + (lane & 15);
    float v = 0.f;
    if (style == 0) {
        int K = (nKT == 2) ? 46 : 256;
        if (k < K) v = ldf(src, k * N + n, f32);
    } else {
        // inp k-order: [act(4), body(10), obj(15), zero(3), agg(128)]
        // phi_w rows:  [act(4), body(10), obj(15), agg(128)]
        if (k < 29) v = ldf(src, k * N + n, f32);
        else if (k >= 32) v = ldf(src, (k - 3) * N + n, f32);
    }
    ws[idx] = (__bf16)v;
}

// Direct B-fragment gather from natural-layout W (fallback when ws too small).
__device__ __forceinline__ bf16x8 gatherB(const void* W, bool f32, int style,
                                          int K, int N, int k0, int n, int q) {
    bf16x8 r;
#pragma unroll
    for (int j = 0; j < 8; ++j) {
        int k = k0 + q * 8 + j;
        bool ok = true;
        if (style == 1) { if (k >= 32) k -= 3; else if (k >= 29) ok = false; }
        if (k >= K) ok = false;
        float v = ok ? ldf(W, k * N + n, f32) : 0.f;
        r[j] = (__bf16)v;
    }
    return r;
}

// ---- main fused kernel ---------------------------------------------------
// 16 batch rows per block. LDS:
//   s_union[0..12288)   : edge-A frags (<=12 mt, 2 kt) ALIASED with h frags (<=3 mt, 8 kt)
//   s_union[12288..14208): rowbuf, 16 rows x 120 = [obs(85)|act(4)|dg(30)|pad]
//   s_inp[12800]        : inp frags, 5 mt x 5 kt x 512
//   s_bias[1664]        : [mp_b 0 |b1 128 |b2 384 |b3 640 |b4 896 |rho1 1152 |rho2 1408]

template <int PC, int PBASE>
__device__ __forceinline__ void buildA(__bf16* sA, const __bf16* rb, const int* s_esrc,
                                       const int* s_pid0, const int* s_pid1, int tid) {
    for (int i = tid; i < 16 * PC * 64; i += 256) {
        int r = i >> 6, k = i & 63;
        int lb = r / PC, p = PBASE + r % PC;
        const __bf16* row = rb + lb * 120;
        __bf16 v = (__bf16)0.f;
        if (k < 10) v = row[k];                                        // body
        else if (k < 14) v = row[85 + (k - 10)];                       // act
        else if (k < 16) v = row[89 + ((k == 14) ? s_pid0[p] : s_pid1[p])];  // dg pair
        else if (k < 31) v = row[10 + s_esrc[p] * 15 + (k - 16)];      // src obj
        else if (k < 46) v = row[10 + (p >> 2) * 15 + (k - 31)];       // dst obj (= p/4)
        sA[((r >> 4) * 2 + (k >> 5)) * 512 + ((((k & 31) >> 3) << 4) + (r & 15)) * 8 + (k & 7)] = v;
    }
}

template <int PC, int PBASE, bool DW>
__device__ __forceinline__ void stage1(const __bf16* Wf, const void* Wn, bool f32,
                                       const __bf16* s_bias, const __bf16* sA,
                                       __bf16* s_inp, int wave, int lane) {
    int q = lane >> 4, c = lane & 15;
    f32x4 zero4 = {0.f, 0.f, 0.f, 0.f};
#pragma unroll
    for (int mtg = 0; mtg < PC / 4; ++mtg) {
        f32x4 acc[4][2];
#pragma unroll
        for (int m = 0; m < 4; ++m) { acc[m][0] = zero4; acc[m][1] = zero4; }
#pragma unroll
        for (int kt = 0; kt < 2; ++kt) {
            bf16x8 bw[2];
#pragma unroll
            for (int n = 0; n < 2; ++n) {
                int nt = wave * 2 + n;
                if constexpr (DW) bw[n] = gatherB(Wn, f32, 0, 46, 128, kt * 32, nt * 16 + c, q);
                else bw[n] = *(const bf16x8*)(Wf + (nt * 2 + kt) * 512 + lane * 8);
            }
#pragma unroll
            for (int m = 0; m < 4; ++m) {
                bf16x8 a = *(const bf16x8*)(sA + ((mtg * 4 + m) * 2 + kt) * 512 + lane * 8);
                acc[m][0] = MFMA(a, bw[0], acc[m][0]);
                acc[m][1] = MFMA(a, bw[1], acc[m][1]);
            }
        }
#pragma unroll
        for (int m = 0; m < 4; ++m)
#pragma unroll
            for (int n = 0; n < 2; ++n) {
                int mt = mtg * 4 + m, nt = wave * 2 + n;
                float bias = (float)s_bias[nt * 16 + c];
                float sum = 0.f;
#pragma unroll
                for (int rr = 0; rr < 4; ++rr) {
                    float z = acc[m][n][rr] + bias;
                    sum += (z > 0.f) ? z : 0.f;
                }
                // quad q holds rows mt*16+q*4 .. +3 = one (b, dst-object) group
                int r0 = mt * 16 + q * 4;
                int lb = r0 / PC;
                int o = (PBASE + (r0 % PC)) >> 2;
                int rinp = lb * 5 + o;
                int kk = 32 + nt * 16 + c;  // agg lives at k = 32..159
                s_inp[((rinp >> 4) * 5 + (kk >> 5)) * 512 +
                      ((((kk & 31) >> 3) << 4) + (rinp & 15)) * 8 + (kk & 7)] = (__bf16)sum;
            }
    }
}

template <int MTN, bool DW>
__device__ __forceinline__ void stage2(int mbase, const __bf16* Wf, const void* Wn, bool f32,
                                       const __bf16* s_bias_b, __bf16* s_h,
                                       const __bf16* s_inp, int wave, int lane) {
    int q = lane >> 4, c = lane & 15;
    f32x4 zero4 = {0.f, 0.f, 0.f, 0.f};
    f32x4 acc[MTN][4];
#pragma unroll
    for (int m = 0; m < MTN; ++m)
#pragma unroll
        for (int n = 0; n < 4; ++n) acc[m][n] = zero4;
#pragma unroll
    for (int kt = 0; kt < 5; ++kt) {
        bf16x8 bw[4];
#pragma unroll
        for (int n = 0; n < 4; ++n) {
            int nt = wave * 4 + n;
            if constexpr (DW) bw[n] = gatherB(Wn, f32, 1, 157, 256, kt * 32, nt * 16 + c, q);
            else bw[n] = *(const bf16x8*)(Wf + (nt * 5 + kt) * 512 + lane * 8);
        }
#pragma unroll
        for (int m = 0; m < MTN; ++m) {
            bf16x8 a = *(const bf16x8*)(s_inp + ((mbase + m) * 5 + kt) * 512 + lane * 8);
#pragma unroll
            for (int n = 0; n < 4; ++n) acc[m][n] = MFMA(a, bw[n], acc[m][n]);
        }
    }
#pragma unroll
    for (int m = 0; m < MTN; ++m)
#pragma unroll
        for (int n = 0; n < 4; ++n) {
            int nt = wave * 4 + n;
            float bias = (float)s_bias_b[nt * 16 + c];
#pragma unroll
            for (int rr = 0; rr < 4; ++rr) {
                float h = acc[m][n][rr] + bias;
                h = (h > 0.f) ? h : 0.f;
                int r = q * 4 + rr;
                int k = nt * 16 + c;
                s_h[(m * 8 + (k >> 5)) * 512 + ((((k & 31) >> 3) << 4) + r) * 8 + (k & 7)] =
                    (__bf16)h;
            }
        }
}

template <int MTN, bool DW>
__device__ __forceinline__ void stage3(int mbase, const __bf16* Wf, const void* Wn, bool f32,
                                       const __bf16* s_bias_b, const __bf16* s_rho,
                                       const __bf16* s_h, float* s_qp, int wave, int lane) {
    int q = lane >> 4, c = lane & 15;
    f32x4 zero4 = {0.f, 0.f, 0.f, 0.f};
    f32x4 acc[MTN][4];
#pragma unroll
    for (int m = 0; m < MTN; ++m)
#pragma unroll
        for (int n = 0; n < 4; ++n) acc[m][n] = zero4;
#pragma unroll
    for (int kt = 0; kt < 8; ++kt) {
        bf16x8 bw[4];
#pragma unroll
        for (int n = 0; n < 4; ++n) {
            int nt = wave * 4 + n;
            if constexpr (DW) bw[n] = gatherB(Wn, f32, 0, 256, 256, kt * 32, nt * 16 + c, q);
            else bw[n] = *(const bf16x8*)(Wf + (nt * 8 + kt) * 512 + lane * 8);
        }
#pragma unroll
        for (int m = 0; m < MTN; ++m) {
            bf16x8 a = *(const bf16x8*)(s_h + (m * 8 + kt) * 512 + lane * 8);
#pragma unroll
            for (int n = 0; n < 4; ++n) acc[m][n] = MFMA(a, bw[n], acc[m][n]);
        }
    }
#pragma unroll
    for (int m = 0; m < MTN; ++m)
#pragma unroll
        for (int n = 0; n < 4; ++n) {
            int nt = wave * 4 + n;
            float bias = (float)s_bias_b[nt * 16 + c];
            float rho = (float)s_rho[nt * 16 + c];
            int r0 = (mbase + m) * 16 + q * 4;  // global row 0..79, b = row/5
            int bfirst = r0 / 5, blast = (r0 + 3) / 5;
            float v0 = 0.f, v1 = 0.f;
#pragma unroll
            for (int rr = 0; rr < 4; ++rr) {
                float z = acc[m][n][rr] + bias;
                z = (z > 0.f) ? z : 0.f;
                z *= rho;
                if ((r0 + rr) / 5 == bfirst) v0 += z; else v1 += z;
            }
#pragma unroll
            for (int mask = 1; mask < 16; mask <<= 1) {
                v0 += __shfl_xor(v0, mask);
                v1 += __shfl_xor(v1, mask);
            }
            if (c == 0) {
                atomicAdd(&s_qp[bfirst], v0);
                if (blast != bfirst) atomicAdd(&s_qp[blast], v1);
            }
        }
}

template <bool DW>
__global__ __launch_bounds__(256, 2) void gn_main(
    const void* __restrict__ obs, const void* __restrict__ act,
    const void* __restrict__ ag, const void* __restrict__ g,
    const void* __restrict__ mp_b, const void* __restrict__ b1,
    const void* __restrict__ b2, const void* __restrict__ b3,
    const void* __restrict__ b4, const void* __restrict__ rw1,
    const void* __restrict__ rb1, const void* __restrict__ rw2,
    const void* __restrict__ rb2, const int* __restrict__ eA,
    const int* __restrict__ eB, const int* __restrict__ pred_ids,
    const int* __restrict__ incoming, const __bf16* __restrict__ wsW,
    const void* __restrict__ mp_w, const void* __restrict__ w1,
    const void* __restrict__ w2, const void* __restrict__ w3,
    const void* __restrict__ w4, float* __restrict__ out, int Btot) {
    __shared__ __align__(16) __bf16 s_union[14208];
    __shared__ __align__(16) __bf16 s_inp[12800];
    __shared__ __bf16 s_bias[1664];
    __shared__ int s_esrc[20], s_pid0[20], s_pid1[20], s_f[2];
    __shared__ float s_q[32];

    int tid = threadIdx.x, lane = tid & 63, wave = tid >> 6;
    __bf16* rb = s_union + 12288;
    int b0 = blockIdx.x * 16;

    // ---- dtype detection ----
    if (tid == 0) { s_f[0] = 0; s_f[1] = 0; }
    __syncthreads();
    {
        const unsigned short* uo = (const unsigned short*)obs;
        const unsigned short* uw = (const unsigned short*)w2;
        int bad = 0;
        for (int i = tid; i < 8192; i += 256)
            if (((uo[i] >> 7) & 0xFF) == 0xFF) bad = 1;
        if (bad) atomicOr(&s_f[0], 1);
        bad = 0;
        for (int i = tid; i < 8192; i += 256)
            if (((uw[i] >> 7) & 0xFF) == 0xFF) bad = 1;
        if (bad) atomicOr(&s_f[1], 1);
    }

    // ---- int width + src/dst disambiguation ----
    bool i64_i = (incoming[1] == 0);
    bool i64_p = (pred_ids[1] == 0);
    bool i64_e = (eA[9] == 0);
    const int* es = (geti(eA, 4, i64_e) == 1) ? eA : eB;

    if (tid < 20) {
        int e = geti(incoming, tid, i64_i);  // tid = o*4+j; edge p=tid has dst o=tid/4
        s_esrc[tid] = geti(es, e, i64_e);
        s_pid0[tid] = geti(pred_ids, 2 * e, i64_p);
        s_pid1[tid] = geti(pred_ids, 2 * e + 1, i64_p);
    }
    if (tid < 32) s_q[tid] = 0.f;
    __syncthreads();
    bool fI = s_f[0] != 0, fW = s_f[1] != 0;

    // ---- biases + rowbuf ----
    for (int i = tid; i < 1664; i += 256) {
        float v;
        if (i < 128) v = ldf(mp_b, i, fW);
        else if (i < 384) v = ldf(b1, i - 128, fW);
        else if (i < 640) v = ldf(b2, i - 384, fW);
        else if (i < 896) v = ldf(b3, i - 640, fW);
        else if (i < 1152) v = ldf(b4, i - 896, fW);
        else if (i < 1408) v = ldf(rw1, i - 1152, fW);
        else v = ldf(rw2, i - 1408, fW);
        s_bias[i] = (__bf16)v;
    }
    for (int i = tid; i < 16 * 120; i += 256) {
        int lb = i / 120, cidx = i % 120;
        int bg = b0 + lb;
        float v = 0.f;
        if (cidx < 85) v = ldf(obs, bg * 85 + cidx, fI);
        else if (cidx < 89) v = ldf(act, bg * 4 + (cidx - 85), fI);
        else if (cidx < 119) {
            int t = cidx - 89;
            v = ldf(g, bg * 30 + t, fI) - ldf(ag, bg * 30 + t, fI);
        }
        rb[i] = (__bf16)v;
    }
    __syncthreads();

    // ---- build inp kt=0 plane (k<32: act,body,obj,zeros) + edge-A chunk0 ----
    for (int i = tid; i < 80 * 32; i += 256) {
        int r = i >> 5, k = i & 31;
        int lb = r / 5, o = r % 5;
        const __bf16* row = rb + lb * 120;
        __bf16 v = (__bf16)0.f;
        if (k < 4) v = row[85 + k];
        else if (k < 14) v = row[k - 4];
        else if (k < 29) v = row[10 + o * 15 + (k - 14)];
        s_inp[(r >> 4) * 2560 + (((k >> 3) << 4) + (r & 15)) * 8 + (k & 7)] = v;
    }
    buildA<12, 0>(s_union, rb, s_esrc, s_pid0, s_pid1, tid);
    __syncthreads();
    stage1<12, 0, DW>(wsW + MP_OFF, mp_w, fW, s_bias, s_union, s_inp, wave, lane);
    __syncthreads();
    buildA<8, 12>(s_union, rb, s_esrc, s_pid0, s_pid1, tid);
    __syncthreads();
    stage1<8, 12, DW>(wsW + MP_OFF, mp_w, fW, s_bias, s_union, s_inp, wave, lane);
    __syncthreads();

    // ---- twin phi/rho phases ----
    for (int P = 0; P < 2; ++P) {
        const __bf16* Wa = wsW + (P ? W3_OFF : W1_OFF);
        const __bf16* Wb = wsW + (P ? W4_OFF : W2_OFF);
        const void* Wan = P ? w3 : w1;
        const void* Wbn = P ? w4 : w2;
        const __bf16* ba = s_bias + (P ? 640 : 128);
        const __bf16* bb = s_bias + (P ? 896 : 384);
        const __bf16* rho = s_bias + (P ? 1408 : 1152);
        float* qp = s_q + P * 16;
        stage2<3, DW>(0, Wa, Wan, fW, ba, s_union, s_inp, wave, lane);
        __syncthreads();
        stage3<3, DW>(0, Wb, Wbn, fW, bb, rho, s_union, qp, wave, lane);
        __syncthreads();
        stage2<2, DW>(3, Wa, Wan, fW, ba, s_union, s_inp, wave, lane);
        __syncthreads();
        stage3<2, DW>(3, Wb, Wbn, fW, bb, rho, s_union, qp, wave, lane);
        __syncthreads();
    }

    if (tid < 16) {
        out[b0 + tid] = s_q[tid] + ldf(rb1, 0, fW);
        out[Btot + b0 + tid] = s_q[16 + tid] + ldf(rb2, 0, fW);
    }
}

extern "C" void kernel_launch(void* const* d_in, const int* in_sizes, int n_in,
                              void* d_out, int out_size, void* d_ws, size_t ws_size,
                              hipStream_t stream) {
    int B = out_size / 2;  // 16384

    // ---- order-robust input resolution by size signature ----
    const void *obs = nullptr, *act = nullptr, *ag = nullptr, *g = nullptr;
    const void *mp_w = nullptr, *mp_b = nullptr;
    const void *w1 = nullptr, *b1 = nullptr, *w2 = nullptr, *b2 = nullptr;
    const void *w3 = nullptr, *b3 = nullptr, *w4 = nullptr, *b4 = nullptr;
    const void *rw1 = nullptr, *rb1 = nullptr, *rw2 = nullptr, *rb2 = nullptr;
    const int *eA = nullptr, *eB = nullptr, *pred = nullptr, *inc = nullptr;
    int c30 = 0, c256 = 0, c1 = 0, c40k = 0, c65k = 0, c20 = 0;
    for (int i = 0; i < n_in; ++i) {
        int sz = in_sizes[i];
        const void* p = d_in[i];
        if (sz == B * 85) obs = p;
        else if (sz == B * 30) { if (c30++ == 0) ag = p; else g = p; }
        else if (sz == 5888) mp_w = p;
        else if (sz == 128) mp_b = p;
        else if (sz == 40192) { if (c40k++ == 0) w1 = p; else w3 = p; }
        else if (sz == 65536 || sz == B * 4) {
            int c = c65k++;
            if (c == 0) act = p; else if (c == 1) w2 = p; else w4 = p;
        }
        else if (sz == 256) {
            int c = c256++;
            if (c == 0) b1 = p; else if (c == 1) b2 = p; else if (c == 2) b3 = p;
            else if (c == 3) b4 = p; else if (c == 4) rw1 = p; else rw2 = p;
        }
        else if (sz == 1) { if (c1++ == 0) rb1 = p; else rb2 = p; }
        else if (sz == 40) pred = (const int*)p;
        else if (sz == 20) {
            int c = c20++;
            if (c == 0) eA = (const int*)p;
            else if (c == 1) eB = (const int*)p;
            else inc = (const int*)p;
        }
    }
    if (!obs || !act || !ag || !g || !mp_w || !mp_b || !w1 || !b1 || !w2 || !b2 ||
        !w3 || !b3 || !w4 || !b4 || !rw1 || !rb1 || !rw2 || !rb2 || !eA || !eB ||
        !pred || !inc) {
        obs = d_in[0]; act = d_in[1]; ag = d_in[2]; g = d_in[3];
        mp_w = d_in[4]; mp_b = d_in[5]; w1 = d_in[6]; b1 = d_in[7];
        w2 = d_in[8]; b2 = d_in[9]; w3 = d_in[10]; b3 = d_in[11];
        w4 = d_in[12]; b4 = d_in[13]; rw1 = d_in[14]; rb1 = d_in[15];
        rw2 = d_in[16]; rb2 = d_in[17];
        eA = (const int*)d_in[18]; eB = (const int*)d_in[19];
        pred = (const int*)d_in[20]; inc = (const int*)d_in[21];
    }

    float* out = (float*)d_out;
    __bf16* wsW = (__bf16*)d_ws;
    bool use_ws = ws_size >= WS_BYTES;
    int grid = B / 16;

    if (use_ws) {
        swz<<<(WS_TOTAL + 255) / 256, 256, 0, stream>>>(mp_w, w1, w2, w3, w4, wsW);
        gn_main<false><<<grid, 256, 0, stream>>>(
            obs, act, ag, g, mp_b, b1, b2, b3, b4, rw1, rb1, rw2, rb2,
            eA, eB, pred, inc, wsW, mp_w, w1, w2, w3, w4, out, B);
    } else {
        gn_main<true><<<grid, 256, 0, stream>>>(
            obs, act, ag, g, mp_b, b1, b2, b3, b4, rw1, rb1, rw2, rb2,
            eA, eB, pred, inc, wsW, mp_w, w1, w2, w3, w4, out, B);
    }
}

// Round 9
// 223.145 us; speedup vs baseline: 87.6612x; 1.0916x over previous
//
#include <hip/hip_runtime.h>
#include <hip/hip_bf16.h>

typedef __bf16 bf16x8 __attribute__((ext_vector_type(8)));
typedef __bf16 bf16x4 __attribute__((ext_vector_type(4)));
typedef float f32x4 __attribute__((ext_vector_type(4)));

#define MFMA(a, b, c) __builtin_amdgcn_mfma_f32_16x16x32_bf16(a, b, c, 0, 0, 0)

// ws layout (bf16 elem offsets) — weights in MFMA B-fragment order:
// frag[(nt*nKT + kt)*64 + lane][j] = W[kt*32 + (lane>>4)*8 + j][nt*16 + (lane&15)]
constexpr int MP_OFF = 0;
constexpr int W1_OFF = 8192;
constexpr int W2_OFF = 49152;
constexpr int W3_OFF = 114688;
constexpr int W4_OFF = 155648;
constexpr int WS_TOTAL = 221184;
constexpr size_t WS_BYTES = (size_t)WS_TOTAL * 2;

__device__ __forceinline__ float ldf(const void* p, int i, bool f32) {
    return f32 ? ((const float*)p)[i] : (float)(((const __bf16*)p)[i]);
}
__device__ __forceinline__ int geti(const int* p, int i, bool i64) {
    return p[i64 ? 2 * i : i];
}

__global__ void swz(const void* __restrict__ mp, const void* __restrict__ w1,
                    const void* __restrict__ w2, const void* __restrict__ w3,
                    const void* __restrict__ w4, __bf16* __restrict__ ws) {
    __shared__ int s_f;
    if (threadIdx.x == 0) s_f = 0;
    __syncthreads();
    {
        const unsigned short* uw = (const unsigned short*)w2;
        int bad = 0;
        for (int i = threadIdx.x; i < 8192; i += 256)
            if (((uw[i] >> 7) & 0xFF) == 0xFF) bad = 1;
        if (bad) atomicOr(&s_f, 1);
    }
    __syncthreads();
    bool f32 = s_f != 0;

    int idx = blockIdx.x * blockDim.x + threadIdx.x;
    if (idx >= WS_TOTAL) return;
    const void* src;
    int local, nKT, N, style;
    if (idx < W1_OFF)      { src = mp; local = idx;          nKT = 2; N = 128; style = 0; }
    else if (idx < W2_OFF) { src = w1; local = idx - W1_OFF; nKT = 5; N = 256; style = 1; }
    else if (idx < W3_OFF) { src = w2; local = idx - W2_OFF; nKT = 8; N = 256; style = 0; }
    else if (idx < W4_OFF) { src = w3; local = idx - W3_OFF; nKT = 5; N = 256; style = 1; }
    else                   { src = w4; local = idx - W4_OFF; nKT = 8; N = 256; style = 0; }
    int j = local & 7, lane = (local >> 3) & 63, t = local >> 9;
    int kt = t % nKT, nt = t / nKT;
    int k = kt * 32 + ((lane >> 4) << 3) + j;
    int n = nt * 16 + (lane & 15);
    float v = 0.f;
    if (style == 0) {
        int K = (nKT == 2) ? 46 : 256;
        if (k < K) v = ldf(src, k * N + n, f32);
    } else {
        // inp k-order: [act4, body10, obj15, zero3, agg128]; W rows: [act4,body10,obj15,agg128]
        if (k < 29) v = ldf(src, k * N + n, f32);
        else if (k >= 32) v = ldf(src, (k - 3) * N + n, f32);
    }
    ws[idx] = (__bf16)v;
}

// Direct B-fragment gather fallback (ws too small). Same lane mapping as A-frag.
__device__ __forceinline__ bf16x8 gatherB(const void* W, bool f32, int style,
                                          int K, int N, int k0, int n, int q) {
    bf16x8 r;
#pragma unroll
    for (int j = 0; j < 8; ++j) {
        int k = k0 + q * 8 + j;
        bool ok = true;
        if (style == 1) { if (k >= 32) k -= 3; else if (k >= 29) ok = false; }
        if (k >= K) ok = false;
        float v = ok ? ldf(W, k * N + n, f32) : 0.f;
        r[j] = (__bf16)v;
    }
    return r;
}

// LDS (54.4 KB total):
//   s_union[0..12288)    : edge-A frags / h frags (aliased)
//   s_union[12288..14208): rowbuf 16 x 120
//   s_inp[12800]         : inp frags, 5 mt x 5 kt x 512
template <int PC, int PBASE>
__device__ __forceinline__ void buildA(__bf16* sA, const __bf16* rb, const int* s_esrc,
                                       const int* s_pid0, const int* s_pid1, int tid) {
    for (int i = tid; i < 16 * PC * 8; i += 256) {
        int r = i >> 3, oct = i & 7;
        int lb = r / PC, p = PBASE + r % PC;
        const __bf16* row = rb + lb * 120;
        bf16x8 v;
#pragma unroll
        for (int j = 0; j < 8; ++j) {
            int k = oct * 8 + j;
            __bf16 x = (__bf16)0.f;
            if (k < 10) x = row[k];
            else if (k < 14) x = row[85 + (k - 10)];
            else if (k < 16) x = row[89 + ((k == 14) ? s_pid0[p] : s_pid1[p])];
            else if (k < 31) x = row[10 + s_esrc[p] * 15 + (k - 16)];
            else if (k < 46) x = row[10 + (p >> 2) * 15 + (k - 31)];
            v[j] = x;
        }
        int t = (r >> 4) * 2 + (oct >> 2);
        int lanep = ((oct & 3) << 4) | (r & 15);
        *(bf16x8*)(sA + t * 512 + lanep * 8) = v;
    }
}

// stage1 (original orientation): A=edges, B=mp_w frags; quad holds one (b,o) group.
template <int PC, int PBASE, bool DW>
__device__ __forceinline__ void stage1(const __bf16* Wf, const void* Wn, bool fW,
                                       const void* mp_b, const __bf16* sA,
                                       __bf16* s_inp, int wave, int lane) {
    int q = lane >> 4, c = lane & 15;
    float mb[2];
#pragma unroll
    for (int n = 0; n < 2; ++n) mb[n] = ldf(mp_b, (wave * 2 + n) * 16 + c, fW);
    f32x4 zero4 = {0.f, 0.f, 0.f, 0.f};
#pragma unroll
    for (int mtg = 0; mtg < PC / 4; ++mtg) {
        f32x4 acc[4][2];
#pragma unroll
        for (int m = 0; m < 4; ++m) { acc[m][0] = zero4; acc[m][1] = zero4; }
#pragma unroll
        for (int kt = 0; kt < 2; ++kt) {
            bf16x8 bw[2];
#pragma unroll
            for (int n = 0; n < 2; ++n) {
                int nt = wave * 2 + n;
                if constexpr (DW) bw[n] = gatherB(Wn, fW, 0, 46, 128, kt * 32, nt * 16 + c, q);
                else bw[n] = *(const bf16x8*)(Wf + (nt * 2 + kt) * 512 + lane * 8);
            }
#pragma unroll
            for (int m = 0; m < 4; ++m) {
                bf16x8 a = *(const bf16x8*)(sA + ((mtg * 4 + m) * 2 + kt) * 512 + lane * 8);
                acc[m][0] = MFMA(a, bw[0], acc[m][0]);
                acc[m][1] = MFMA(a, bw[1], acc[m][1]);
            }
        }
#pragma unroll
        for (int m = 0; m < 4; ++m)
#pragma unroll
            for (int n = 0; n < 2; ++n) {
                int mt = mtg * 4 + m, nt = wave * 2 + n;
                float sum = 0.f;
#pragma unroll
                for (int rr = 0; rr < 4; ++rr) {
                    float z = acc[m][n][rr] + mb[n];
                    sum += (z > 0.f) ? z : 0.f;
                }
                int r0 = mt * 16 + q * 4;
                int lb = r0 / PC;
                int o = (PBASE + (r0 % PC)) >> 2;
                int rinp = lb * 5 + o;
                int kk = 32 + nt * 16 + c;
                s_inp[((rinp >> 4) * 5 + (kk >> 5)) * 512 +
                      ((((kk & 31) >> 3) << 4) + (rinp & 15)) * 8 + (kk & 7)] = (__bf16)sum;
            }
    }
}

// stage2 SWAPPED: D'[hcol][row] = MFMA(A=W1-frag, B=inp-frag).
// Epilogue: relu(+bias) -> one ds_write_b64 lands in exact A-frag layout for stage3.
template <int MTN, bool DW>
__device__ __forceinline__ void stage2s(int mbase, const __bf16* Wf, const void* Wn,
                                        bool fW, const void* Ba, __bf16* s_h,
                                        const __bf16* s_inp, int wave, int lane) {
    int q = lane >> 4, c = lane & 15;
    f32x4 zero4 = {0.f, 0.f, 0.f, 0.f};
    float bias_r[4][4];
#pragma unroll
    for (int n = 0; n < 4; ++n)
#pragma unroll
        for (int rg = 0; rg < 4; ++rg)
            bias_r[n][rg] = ldf(Ba, (wave * 4 + n) * 16 + q * 4 + rg, fW);
#pragma unroll
    for (int n = 0; n < 4; ++n) {
        int ht = wave * 4 + n;
        bf16x8 aw[5];
#pragma unroll
        for (int kt = 0; kt < 5; ++kt) {
            if constexpr (DW) aw[kt] = gatherB(Wn, fW, 1, 157, 256, kt * 32, ht * 16 + c, q);
            else aw[kt] = *(const bf16x8*)(Wf + (ht * 5 + kt) * 512 + lane * 8);
        }
        f32x4 acc[MTN];
#pragma unroll
        for (int m = 0; m < MTN; ++m) acc[m] = zero4;
#pragma unroll
        for (int kt = 0; kt < 5; ++kt) {
#pragma unroll
            for (int m = 0; m < MTN; ++m) {
                bf16x8 b = *(const bf16x8*)(s_inp + ((mbase + m) * 5 + kt) * 512 + lane * 8);
                acc[m] = MFMA(aw[kt], b, acc[m]);
            }
        }
#pragma unroll
        for (int m = 0; m < MTN; ++m) {
            bf16x4 hv;
#pragma unroll
            for (int rg = 0; rg < 4; ++rg) {
                float z = acc[m][rg] + bias_r[n][rg];
                hv[rg] = (__bf16)((z > 0.f) ? z : 0.f);
            }
            *(bf16x4*)(s_h + (m * 8 + (ht >> 1)) * 512 +
                       ((((ht & 1) * 2 + (q >> 1)) << 4) | c) * 8 + ((q & 1) << 2)) = hv;
        }
    }
}

// stage3 SWAPPED: D'[ncol][row] = MFMA(A=W2-frag, B=h-frag). Reduction:
// in-lane over regs/nt, 2 shuffles over quads, 16 LDS atomics per (wave, m-tile).
template <int MTN, bool DW>
__device__ __forceinline__ void stage3s(int mbase, const __bf16* Wf, const void* Wn,
                                        bool fW, const void* Bb, const void* Rh,
                                        const __bf16* s_h, float* s_qp, int wave, int lane) {
    int q = lane >> 4, c = lane & 15;
    f32x4 zero4 = {0.f, 0.f, 0.f, 0.f};
    float bias_r[4][4], rho_r[4][4];
#pragma unroll
    for (int n = 0; n < 4; ++n)
#pragma unroll
        for (int rg = 0; rg < 4; ++rg) {
            int ncol = (wave * 4 + n) * 16 + q * 4 + rg;
            bias_r[n][rg] = ldf(Bb, ncol, fW);
            rho_r[n][rg] = ldf(Rh, ncol, fW);
        }
    float rowsum[MTN];
#pragma unroll
    for (int m = 0; m < MTN; ++m) rowsum[m] = 0.f;
#pragma unroll
    for (int n = 0; n < 4; ++n) {
        int nt = wave * 4 + n;
        bf16x8 aw[8];
#pragma unroll
        for (int kt = 0; kt < 8; ++kt) {
            if constexpr (DW) aw[kt] = gatherB(Wn, fW, 0, 256, 256, kt * 32, nt * 16 + c, q);
            else aw[kt] = *(const bf16x8*)(Wf + (nt * 8 + kt) * 512 + lane * 8);
        }
        f32x4 acc[MTN];
#pragma unroll
        for (int m = 0; m < MTN; ++m) acc[m] = zero4;
#pragma unroll
        for (int kt = 0; kt < 8; ++kt) {
#pragma unroll
            for (int m = 0; m < MTN; ++m) {
                bf16x8 b = *(const bf16x8*)(s_h + (m * 8 + kt) * 512 + lane * 8);
                acc[m] = MFMA(aw[kt], b, acc[m]);
            }
        }
#pragma unroll
        for (int m = 0; m < MTN; ++m)
#pragma unroll
            for (int rg = 0; rg < 4; ++rg) {
                float z = acc[m][rg] + bias_r[n][rg];
                z = (z > 0.f) ? z : 0.f;
                rowsum[m] += z * rho_r[n][rg];
            }
    }
#pragma unroll
    for (int m = 0; m < MTN; ++m) {
        float v = rowsum[m];
        v += __shfl_xor(v, 16);
        v += __shfl_xor(v, 32);
        if (q == 0) {
            int r0 = (mbase + m) * 16 + c;  // rinp = b*5+o
            atomicAdd(&s_qp[r0 / 5], v);
        }
    }
}

template <bool DW>
__global__ __launch_bounds__(256, 3) void gn_main(
    const void* __restrict__ obs, const void* __restrict__ act,
    const void* __restrict__ ag, const void* __restrict__ g,
    const void* __restrict__ mp_b, const void* __restrict__ b1,
    const void* __restrict__ b2, const void* __restrict__ b3,
    const void* __restrict__ b4, const void* __restrict__ rw1,
    const void* __restrict__ rb1, const void* __restrict__ rw2,
    const void* __restrict__ rb2, const int* __restrict__ eA,
    const int* __restrict__ eB, const int* __restrict__ pred_ids,
    const int* __restrict__ incoming, const __bf16* __restrict__ wsW,
    const void* __restrict__ mp_w, const void* __restrict__ w1,
    const void* __restrict__ w2, const void* __restrict__ w3,
    const void* __restrict__ w4, float* __restrict__ out, int Btot) {
    __shared__ __align__(16) __bf16 s_union[14208];
    __shared__ __align__(16) __bf16 s_inp[12800];
    __shared__ int s_esrc[20], s_pid0[20], s_pid1[20], s_f[2];
    __shared__ float s_q[32];

    int tid = threadIdx.x, lane = tid & 63, wave = tid >> 6;
    __bf16* rb = s_union + 12288;
    int b0 = blockIdx.x * 16;

    if (tid == 0) { s_f[0] = 0; s_f[1] = 0; }
    __syncthreads();
    {
        const unsigned short* uo = (const unsigned short*)obs;
        const unsigned short* uw = (const unsigned short*)w2;
        int bad = 0;
        for (int i = tid; i < 8192; i += 256)
            if (((uo[i] >> 7) & 0xFF) == 0xFF) bad = 1;
        if (bad) atomicOr(&s_f[0], 1);
        bad = 0;
        for (int i = tid; i < 8192; i += 256)
            if (((uw[i] >> 7) & 0xFF) == 0xFF) bad = 1;
        if (bad) atomicOr(&s_f[1], 1);
    }

    bool i64_i = (incoming[1] == 0);
    bool i64_p = (pred_ids[1] == 0);
    bool i64_e = (eA[9] == 0);
    const int* es = (geti(eA, 4, i64_e) == 1) ? eA : eB;

    if (tid < 20) {
        int e = geti(incoming, tid, i64_i);  // tid = o*4+j; edge p=tid has dst o=tid/4
        s_esrc[tid] = geti(es, e, i64_e);
        s_pid0[tid] = geti(pred_ids, 2 * e, i64_p);
        s_pid1[tid] = geti(pred_ids, 2 * e + 1, i64_p);
    }
    if (tid < 32) s_q[tid] = 0.f;
    __syncthreads();
    bool fI = s_f[0] != 0, fW = s_f[1] != 0;

    for (int i = tid; i < 16 * 120; i += 256) {
        int lb = i / 120, cidx = i % 120;
        int bg = b0 + lb;
        float v = 0.f;
        if (cidx < 85) v = ldf(obs, bg * 85 + cidx, fI);
        else if (cidx < 89) v = ldf(act, bg * 4 + (cidx - 85), fI);
        else if (cidx < 119) {
            int t = cidx - 89;
            v = ldf(g, bg * 30 + t, fI) - ldf(ag, bg * 30 + t, fI);
        }
        rb[i] = (__bf16)v;
    }
    __syncthreads();

    // inp kt=0 plane (k<32) as b128 blocks
    for (int i = tid; i < 80 * 4; i += 256) {
        int r = i >> 2, oct = i & 3;
        int lb = r / 5, o = r % 5;
        const __bf16* row = rb + lb * 120;
        bf16x8 v;
#pragma unroll
        for (int j = 0; j < 8; ++j) {
            int k = oct * 8 + j;
            __bf16 x = (__bf16)0.f;
            if (k < 4) x = row[85 + k];
            else if (k < 14) x = row[k - 4];
            else if (k < 29) x = row[10 + o * 15 + (k - 14)];
            v[j] = x;
        }
        *(bf16x8*)(s_inp + (r >> 4) * 2560 + ((oct << 4) | (r & 15)) * 8) = v;
    }
    buildA<12, 0>(s_union, rb, s_esrc, s_pid0, s_pid1, tid);
    __syncthreads();
    stage1<12, 0, DW>(wsW + MP_OFF, mp_w, fW, mp_b, s_union, s_inp, wave, lane);
    __syncthreads();
    buildA<8, 12>(s_union, rb, s_esrc, s_pid0, s_pid1, tid);
    __syncthreads();
    stage1<8, 12, DW>(wsW + MP_OFF, mp_w, fW, mp_b, s_union, s_inp, wave, lane);
    __syncthreads();

    for (int P = 0; P < 2; ++P) {
        const __bf16* Wa = wsW + (P ? W3_OFF : W1_OFF);
        const __bf16* Wb = wsW + (P ? W4_OFF : W2_OFF);
        const void* Wan = P ? w3 : w1;
        const void* Wbn = P ? w4 : w2;
        const void* ba = P ? b3 : b1;
        const void* bb = P ? b4 : b2;
        const void* rho = P ? rw2 : rw1;
        float* qp = s_q + P * 16;
        stage2s<3, DW>(0, Wa, Wan, fW, ba, s_union, s_inp, wave, lane);
        __syncthreads();
        stage3s<3, DW>(0, Wb, Wbn, fW, bb, rho, s_union, qp, wave, lane);
        __syncthreads();
        stage2s<2, DW>(3, Wa, Wan, fW, ba, s_union, s_inp, wave, lane);
        __syncthreads();
        stage3s<2, DW>(3, Wb, Wbn, fW, bb, rho, s_union, qp, wave, lane);
        __syncthreads();
    }

    if (tid < 16) {
        out[b0 + tid] = s_q[tid] + ldf(rb1, 0, fW);
        out[Btot + b0 + tid] = s_q[16 + tid] + ldf(rb2, 0, fW);
    }
}

extern "C" void kernel_launch(void* const* d_in, const int* in_sizes, int n_in,
                              void* d_out, int out_size, void* d_ws, size_t ws_size,
                              hipStream_t stream) {
    int B = out_size / 2;  // 16384

    const void *obs = nullptr, *act = nullptr, *ag = nullptr, *g = nullptr;
    const void *mp_w = nullptr, *mp_b = nullptr;
    const void *w1 = nullptr, *b1 = nullptr, *w2 = nullptr, *b2 = nullptr;
    const void *w3 = nullptr, *b3 = nullptr, *w4 = nullptr, *b4 = nullptr;
    const void *rw1 = nullptr, *rb1 = nullptr, *rw2 = nullptr, *rb2 = nullptr;
    const int *eA = nullptr, *eB = nullptr, *pred = nullptr, *inc = nullptr;
    int c30 = 0, c256 = 0, c1 = 0, c40k = 0, c65k = 0, c20 = 0;
    for (int i = 0; i < n_in; ++i) {
        int sz = in_sizes[i];
        const void* p = d_in[i];
        if (sz == B * 85) obs = p;
        else if (sz == B * 30) { if (c30++ == 0) ag = p; else g = p; }
        else if (sz == 5888) mp_w = p;
        else if (sz == 128) mp_b = p;
        else if (sz == 40192) { if (c40k++ == 0) w1 = p; else w3 = p; }
        else if (sz == 65536 || sz == B * 4) {
            int c = c65k++;
            if (c == 0) act = p; else if (c == 1) w2 = p; else w4 = p;
        }
        else if (sz == 256) {
            int c = c256++;
            if (c == 0) b1 = p; else if (c == 1) b2 = p; else if (c == 2) b3 = p;
            else if (c == 3) b4 = p; else if (c == 4) rw1 = p; else rw2 = p;
        }
        else if (sz == 1) { if (c1++ == 0) rb1 = p; else rb2 = p; }
        else if (sz == 40) pred = (const int*)p;
        else if (sz == 20) {
            int c = c20++;
            if (c == 0) eA = (const int*)p;
            else if (c == 1) eB = (const int*)p;
            else inc = (const int*)p;
        }
    }
    if (!obs || !act || !ag || !g || !mp_w || !mp_b || !w1 || !b1 || !w2 || !b2 ||
        !w3 || !b3 || !w4 || !b4 || !rw1 || !rb1 || !rw2 || !rb2 || !eA || !eB ||
        !pred || !inc) {
        obs = d_in[0]; act = d_in[1]; ag = d_in[2]; g = d_in[3];
        mp_w = d_in[4]; mp_b = d_in[5]; w1 = d_in[6]; b1 = d_in[7];
        w2 = d_in[8]; b2 = d_in[9]; w3 = d_in[10]; b3 = d_in[11];
        w4 = d_in[12]; b4 = d_in[13]; rw1 = d_in[14]; rb1 = d_in[15];
        rw2 = d_in[16]; rb2 = d_in[17];
        eA = (const int*)d_in[18]; eB = (const int*)d_in[19];
        pred = (const int*)d_in[20]; inc = (const int*)d_in[21];
    }

    float* out = (float*)d_out;
    __bf16* wsW = (__bf16*)d_ws;
    bool use_ws = ws_size >= WS_BYTES;
    int grid = B / 16;

    if (use_ws) {
        swz<<<(WS_TOTAL + 255) / 256, 256, 0, stream>>>(mp_w, w1, w2, w3, w4, wsW);
        gn_main<false><<<grid, 256, 0, stream>>>(
            obs, act, ag, g, mp_b, b1, b2, b3, b4, rw1, rb1, rw2, rb2,
            eA, eB, pred, inc, wsW, mp_w, w1, w2, w3, w4, out, B);
    } else {
        gn_main<true><<<grid, 256, 0, stream>>>(
            obs, act, ag, g, mp_b, b1, b2, b3, b4, rw1, rb1, rw2, rb2,
            eA, eB, pred, inc, wsW, mp_w, w1, w2, w3, w4, out, B);
    }
}

// Round 10
// 214.588 us; speedup vs baseline: 91.1569x; 1.0399x over previous
//
#include <hip/hip_runtime.h>
#include <hip/hip_bf16.h>

typedef __bf16 bf16x8 __attribute__((ext_vector_type(8)));
typedef __bf16 bf16x4 __attribute__((ext_vector_type(4)));
typedef float f32x4 __attribute__((ext_vector_type(4)));

#define MFMA(a, b, c) __builtin_amdgcn_mfma_f32_16x16x32_bf16(a, b, c, 0, 0, 0)

// ws layout (bf16 elem offsets) — weights in MFMA B-fragment order:
// frag[(nt*nKT + kt)*64 + lane][j] = W[kt*32 + (lane>>4)*8 + j][nt*16 + (lane&15)]
constexpr int MP_OFF = 0;
constexpr int W1_OFF = 8192;
constexpr int W2_OFF = 49152;
constexpr int W3_OFF = 114688;
constexpr int W4_OFF = 155648;
constexpr int WS_TOTAL = 221184;
constexpr size_t WS_BYTES = (size_t)WS_TOTAL * 2;

__device__ __forceinline__ float ldf(const void* p, int i, bool f32) {
    return f32 ? ((const float*)p)[i] : (float)(((const __bf16*)p)[i]);
}
__device__ __forceinline__ int geti(const int* p, int i, bool i64) {
    return p[i64 ? 2 * i : i];
}

// One-block dtype detector: fp32 misread as bf16 shows exponent-0xFF halfwords.
__global__ void detect(const unsigned short* __restrict__ uo,
                       const unsigned short* __restrict__ uw, int* __restrict__ flags) {
    __shared__ int s0, s1;
    if (threadIdx.x == 0) { s0 = 0; s1 = 0; }
    __syncthreads();
    int b0 = 0, b1 = 0;
    for (int i = threadIdx.x; i < 8192; i += 256) {
        if (((uo[i] >> 7) & 0xFF) == 0xFF) b0 = 1;
        if (((uw[i] >> 7) & 0xFF) == 0xFF) b1 = 1;
    }
    if (b0) atomicOr(&s0, 1);
    if (b1) atomicOr(&s1, 1);
    __syncthreads();
    if (threadIdx.x == 0) { flags[0] = s0; flags[1] = s1; }
}

// Read-side swizzle: thread <-> (padded-k, n) source-linear. Reads coalesced;
// scattered 2B writes drain without stalling. Pads write 0 (full coverage).
__global__ void swz(const void* __restrict__ mp, const void* __restrict__ w1,
                    const void* __restrict__ w2, const void* __restrict__ w3,
                    const void* __restrict__ w4, __bf16* __restrict__ ws,
                    const int* __restrict__ flags) {
    bool f32 = flags[1] != 0;
    int idx = blockIdx.x * blockDim.x + threadIdx.x;
    if (idx >= WS_TOTAL) return;
    const void* src;
    int base, local, nKT, nsh, style, K;
    if (idx < W1_OFF)      { src = mp; base = MP_OFF; local = idx;          nKT = 2; nsh = 7; style = 0; K = 46; }
    else if (idx < W2_OFF) { src = w1; base = W1_OFF; local = idx - W1_OFF; nKT = 5; nsh = 8; style = 1; K = 157; }
    else if (idx < W3_OFF) { src = w2; base = W2_OFF; local = idx - W2_OFF; nKT = 8; nsh = 8; style = 0; K = 256; }
    else if (idx < W4_OFF) { src = w3; base = W3_OFF; local = idx - W3_OFF; nKT = 5; nsh = 8; style = 1; K = 157; }
    else                   { src = w4; base = W4_OFF; local = idx - W4_OFF; nKT = 8; nsh = 8; style = 0; K = 256; }
    int N = 1 << nsh;
    int kp = local >> nsh, n = local & (N - 1);
    int ks = kp;
    bool ok = true;
    if (style == 1) { if (kp >= 32) ks = kp - 3; else if (kp >= 29) ok = false; }
    if (ks >= K) ok = false;
    float v = ok ? ldf(src, ks * N + n, f32) : 0.f;
    int dst = ((n >> 4) * nKT + (kp >> 5)) * 512 +
              (((((kp >> 3) & 3)) << 4) | (n & 15)) * 8 + (kp & 7);
    ws[base + dst] = (__bf16)v;
}

// Direct B-fragment gather fallback (ws too small). Same lane mapping as A-frag.
__device__ __forceinline__ bf16x8 gatherB(const void* W, bool f32, int style,
                                          int K, int N, int k0, int n, int q) {
    bf16x8 r;
#pragma unroll
    for (int j = 0; j < 8; ++j) {
        int k = k0 + q * 8 + j;
        bool ok = true;
        if (style == 1) { if (k >= 32) k -= 3; else if (k >= 29) ok = false; }
        if (k >= K) ok = false;
        float v = ok ? ldf(W, k * N + n, f32) : 0.f;
        r[j] = (__bf16)v;
    }
    return r;
}

// LDS (54,256 B total -> alloc 54,272 -> 3 blocks/CU):
//   s_union[0..12288)    : edge-A frags / h frags (aliased)
//   s_union[12288..14208): rowbuf 16 x 120 (dead after buildA<8,12>; s_q aliases its head)
//   s_inp[12800]         : inp frags, 5 mt x 5 kt x 512
template <int PC, int PBASE>
__device__ __forceinline__ void buildA(__bf16* sA, const __bf16* rb, const int* s_esrc,
                                       const int* s_pid0, const int* s_pid1, int tid) {
    for (int i = tid; i < 16 * PC * 8; i += 256) {
        int r = i >> 3, oct = i & 7;
        int lb = r / PC, p = PBASE + r % PC;
        const __bf16* row = rb + lb * 120;
        bf16x8 v;
#pragma unroll
        for (int j = 0; j < 8; ++j) {
            int k = oct * 8 + j;
            __bf16 x = (__bf16)0.f;
            if (k < 10) x = row[k];
            else if (k < 14) x = row[85 + (k - 10)];
            else if (k < 16) x = row[89 + ((k == 14) ? s_pid0[p] : s_pid1[p])];
            else if (k < 31) x = row[10 + s_esrc[p] * 15 + (k - 16)];
            else if (k < 46) x = row[10 + (p >> 2) * 15 + (k - 31)];
            v[j] = x;
        }
        int t = (r >> 4) * 2 + (oct >> 2);
        int lanep = ((oct & 3) << 4) | (r & 15);
        *(bf16x8*)(sA + t * 512 + lanep * 8) = v;
    }
}

// stage1 (original orientation): A=edges, B=mp_w frags; quad holds one (b,o) group.
template <int PC, int PBASE, bool DW>
__device__ __forceinline__ void stage1(const __bf16* Wf, const void* Wn, bool fW,
                                       const void* mp_b, const __bf16* sA,
                                       __bf16* s_inp, int wave, int lane) {
    int q = lane >> 4, c = lane & 15;
    float mb[2];
#pragma unroll
    for (int n = 0; n < 2; ++n) mb[n] = ldf(mp_b, (wave * 2 + n) * 16 + c, fW);
    f32x4 zero4 = {0.f, 0.f, 0.f, 0.f};
#pragma unroll
    for (int mtg = 0; mtg < PC / 4; ++mtg) {
        f32x4 acc[4][2];
#pragma unroll
        for (int m = 0; m < 4; ++m) { acc[m][0] = zero4; acc[m][1] = zero4; }
#pragma unroll
        for (int kt = 0; kt < 2; ++kt) {
            bf16x8 bw[2];
#pragma unroll
            for (int n = 0; n < 2; ++n) {
                int nt = wave * 2 + n;
                if constexpr (DW) bw[n] = gatherB(Wn, fW, 0, 46, 128, kt * 32, nt * 16 + c, q);
                else bw[n] = *(const bf16x8*)(Wf + (nt * 2 + kt) * 512 + lane * 8);
            }
#pragma unroll
            for (int m = 0; m < 4; ++m) {
                bf16x8 a = *(const bf16x8*)(sA + ((mtg * 4 + m) * 2 + kt) * 512 + lane * 8);
                acc[m][0] = MFMA(a, bw[0], acc[m][0]);
                acc[m][1] = MFMA(a, bw[1], acc[m][1]);
            }
        }
#pragma unroll
        for (int m = 0; m < 4; ++m)
#pragma unroll
            for (int n = 0; n < 2; ++n) {
                int mt = mtg * 4 + m, nt = wave * 2 + n;
                float sum = 0.f;
#pragma unroll
                for (int rr = 0; rr < 4; ++rr) {
                    float z = acc[m][n][rr] + mb[n];
                    sum += (z > 0.f) ? z : 0.f;
                }
                int r0 = mt * 16 + q * 4;
                int lb = r0 / PC;
                int o = (PBASE + (r0 % PC)) >> 2;
                int rinp = lb * 5 + o;
                int kk = 32 + nt * 16 + c;
                s_inp[((rinp >> 4) * 5 + (kk >> 5)) * 512 +
                      ((((kk & 31) >> 3) << 4) + (rinp & 15)) * 8 + (kk & 7)] = (__bf16)sum;
            }
    }
}

// stage2 SWAPPED: D'[hcol][row] = MFMA(A=W1-frag, B=inp-frag).
// Epilogue: relu(+bias) -> one ds_write_b64 lands in exact A-frag layout for stage3.
template <int MTN, bool DW>
__device__ __forceinline__ void stage2s(int mbase, const __bf16* Wf, const void* Wn,
                                        bool fW, const void* Ba, __bf16* s_h,
                                        const __bf16* s_inp, int wave, int lane) {
    int q = lane >> 4, c = lane & 15;
    f32x4 zero4 = {0.f, 0.f, 0.f, 0.f};
    float bias_r[4][4];
#pragma unroll
    for (int n = 0; n < 4; ++n)
#pragma unroll
        for (int rg = 0; rg < 4; ++rg)
            bias_r[n][rg] = ldf(Ba, (wave * 4 + n) * 16 + q * 4 + rg, fW);
#pragma unroll
    for (int n = 0; n < 4; ++n) {
        int ht = wave * 4 + n;
        bf16x8 aw[5];
#pragma unroll
        for (int kt = 0; kt < 5; ++kt) {
            if constexpr (DW) aw[kt] = gatherB(Wn, fW, 1, 157, 256, kt * 32, ht * 16 + c, q);
            else aw[kt] = *(const bf16x8*)(Wf + (ht * 5 + kt) * 512 + lane * 8);
        }
        f32x4 acc[MTN];
#pragma unroll
        for (int m = 0; m < MTN; ++m) acc[m] = zero4;
#pragma unroll
        for (int kt = 0; kt < 5; ++kt) {
#pragma unroll
            for (int m = 0; m < MTN; ++m) {
                bf16x8 b = *(const bf16x8*)(s_inp + ((mbase + m) * 5 + kt) * 512 + lane * 8);
                acc[m] = MFMA(aw[kt], b, acc[m]);
            }
        }
#pragma unroll
        for (int m = 0; m < MTN; ++m) {
            bf16x4 hv;
#pragma unroll
            for (int rg = 0; rg < 4; ++rg) {
                float z = acc[m][rg] + bias_r[n][rg];
                hv[rg] = (__bf16)((z > 0.f) ? z : 0.f);
            }
            *(bf16x4*)(s_h + (m * 8 + (ht >> 1)) * 512 +
                       ((((ht & 1) * 2 + (q >> 1)) << 4) | c) * 8 + ((q & 1) << 2)) = hv;
        }
    }
}

// stage3 SWAPPED: D'[ncol][row] = MFMA(A=W2-frag, B=h-frag). Reduction:
// in-lane over regs/nt, 2 shuffles over quads, 16 LDS atomics per (wave, m-tile).
template <int MTN, bool DW>
__device__ __forceinline__ void stage3s(int mbase, const __bf16* Wf, const void* Wn,
                                        bool fW, const void* Bb, const void* Rh,
                                        const __bf16* s_h, float* s_qp, int wave, int lane) {
    int q = lane >> 4, c = lane & 15;
    f32x4 zero4 = {0.f, 0.f, 0.f, 0.f};
    float bias_r[4][4], rho_r[4][4];
#pragma unroll
    for (int n = 0; n < 4; ++n)
#pragma unroll
        for (int rg = 0; rg < 4; ++rg) {
            int ncol = (wave * 4 + n) * 16 + q * 4 + rg;
            bias_r[n][rg] = ldf(Bb, ncol, fW);
            rho_r[n][rg] = ldf(Rh, ncol, fW);
        }
    float rowsum[MTN];
#pragma unroll
    for (int m = 0; m < MTN; ++m) rowsum[m] = 0.f;
#pragma unroll
    for (int n = 0; n < 4; ++n) {
        int nt = wave * 4 + n;
        bf16x8 aw[8];
#pragma unroll
        for (int kt = 0; kt < 8; ++kt) {
            if constexpr (DW) aw[kt] = gatherB(Wn, fW, 0, 256, 256, kt * 32, nt * 16 + c, q);
            else aw[kt] = *(const bf16x8*)(Wf + (nt * 8 + kt) * 512 + lane * 8);
        }
        f32x4 acc[MTN];
#pragma unroll
        for (int m = 0; m < MTN; ++m) acc[m] = zero4;
#pragma unroll
        for (int kt = 0; kt < 8; ++kt) {
#pragma unroll
            for (int m = 0; m < MTN; ++m) {
                bf16x8 b = *(const bf16x8*)(s_h + (m * 8 + kt) * 512 + lane * 8);
                acc[m] = MFMA(aw[kt], b, acc[m]);
            }
        }
#pragma unroll
        for (int m = 0; m < MTN; ++m)
#pragma unroll
            for (int rg = 0; rg < 4; ++rg) {
                float z = acc[m][rg] + bias_r[n][rg];
                z = (z > 0.f) ? z : 0.f;
                rowsum[m] += z * rho_r[n][rg];
            }
    }
#pragma unroll
    for (int m = 0; m < MTN; ++m) {
        float v = rowsum[m];
        v += __shfl_xor(v, 16);
        v += __shfl_xor(v, 32);
        if (q == 0) {
            int r0 = (mbase + m) * 16 + c;  // rinp = b*5+o
            atomicAdd(&s_qp[r0 / 5], v);
        }
    }
}

template <bool DW>
__global__ __launch_bounds__(256, 3) void gn_main(
    const void* __restrict__ obs, const void* __restrict__ act,
    const void* __restrict__ ag, const void* __restrict__ g,
    const void* __restrict__ mp_b, const void* __restrict__ b1,
    const void* __restrict__ b2, const void* __restrict__ b3,
    const void* __restrict__ b4, const void* __restrict__ rw1,
    const void* __restrict__ rb1, const void* __restrict__ rw2,
    const void* __restrict__ rb2, const int* __restrict__ eA,
    const int* __restrict__ eB, const int* __restrict__ pred_ids,
    const int* __restrict__ incoming, const __bf16* __restrict__ wsW,
    const void* __restrict__ mp_w, const void* __restrict__ w1,
    const void* __restrict__ w2, const void* __restrict__ w3,
    const void* __restrict__ w4, const int* __restrict__ flags,
    float* __restrict__ out, int Btot) {
    __shared__ __align__(16) __bf16 s_union[14208];
    __shared__ __align__(16) __bf16 s_inp[12800];
    __shared__ int s_esrc[20], s_pid0[20], s_pid1[20];

    int tid = threadIdx.x, lane = tid & 63, wave = tid >> 6;
    __bf16* rb = s_union + 12288;
    float* s_q = (float*)(s_union + 12288);  // aliases rowbuf head (dead by stage3)
    int b0 = blockIdx.x * 16;

    // ---- dtype flags ----
    bool fI, fW;
    if constexpr (DW) {
        const unsigned short* uo = (const unsigned short*)obs;
        const unsigned short* uw = (const unsigned short*)w2;
        int d0 = 0, d1 = 0;
        for (int i = lane; i < 8192; i += 64) {
            if (((uo[i] >> 7) & 0xFF) == 0xFF) d0 = 1;
            if (((uw[i] >> 7) & 0xFF) == 0xFF) d1 = 1;
        }
        fI = __ballot(d0) != 0;
        fW = __ballot(d1) != 0;
    } else {
        fI = flags[0] != 0;
        fW = flags[1] != 0;
    }

    // ---- int width + src/dst disambiguation ----
    bool i64_i = (incoming[1] == 0);
    bool i64_p = (pred_ids[1] == 0);
    bool i64_e = (eA[9] == 0);
    const int* es = (geti(eA, 4, i64_e) == 1) ? eA : eB;

    if (tid < 20) {
        int e = geti(incoming, tid, i64_i);  // tid = o*4+j; edge p=tid has dst o=tid/4
        s_esrc[tid] = geti(es, e, i64_e);
        s_pid0[tid] = geti(pred_ids, 2 * e, i64_p);
        s_pid1[tid] = geti(pred_ids, 2 * e + 1, i64_p);
    }

    for (int i = tid; i < 16 * 120; i += 256) {
        int lb = i / 120, cidx = i % 120;
        int bg = b0 + lb;
        float v = 0.f;
        if (cidx < 85) v = ldf(obs, bg * 85 + cidx, fI);
        else if (cidx < 89) v = ldf(act, bg * 4 + (cidx - 85), fI);
        else if (cidx < 119) {
            int t = cidx - 89;
            v = ldf(g, bg * 30 + t, fI) - ldf(ag, bg * 30 + t, fI);
        }
        rb[i] = (__bf16)v;
    }
    __syncthreads();

    // inp kt=0 plane (k<32) as b128 blocks
    for (int i = tid; i < 80 * 4; i += 256) {
        int r = i >> 2, oct = i & 3;
        int lb = r / 5, o = r % 5;
        const __bf16* row = rb + lb * 120;
        bf16x8 v;
#pragma unroll
        for (int j = 0; j < 8; ++j) {
            int k = oct * 8 + j;
            __bf16 x = (__bf16)0.f;
            if (k < 4) x = row[85 + k];
            else if (k < 14) x = row[k - 4];
            else if (k < 29) x = row[10 + o * 15 + (k - 14)];
            v[j] = x;
        }
        *(bf16x8*)(s_inp + (r >> 4) * 2560 + ((oct << 4) | (r & 15)) * 8) = v;
    }
    buildA<12, 0>(s_union, rb, s_esrc, s_pid0, s_pid1, tid);
    __syncthreads();
    stage1<12, 0, DW>(wsW + MP_OFF, mp_w, fW, mp_b, s_union, s_inp, wave, lane);
    __syncthreads();
    buildA<8, 12>(s_union, rb, s_esrc, s_pid0, s_pid1, tid);
    __syncthreads();
    if (tid < 32) s_q[tid] = 0.f;  // rowbuf dead from here on
    stage1<8, 12, DW>(wsW + MP_OFF, mp_w, fW, mp_b, s_union, s_inp, wave, lane);
    __syncthreads();

    for (int P = 0; P < 2; ++P) {
        const __bf16* Wa = wsW + (P ? W3_OFF : W1_OFF);
        const __bf16* Wb = wsW + (P ? W4_OFF : W2_OFF);
        const void* Wan = P ? w3 : w1;
        const void* Wbn = P ? w4 : w2;
        const void* ba = P ? b3 : b1;
        const void* bb = P ? b4 : b2;
        const void* rho = P ? rw2 : rw1;
        float* qp = s_q + P * 16;
        stage2s<3, DW>(0, Wa, Wan, fW, ba, s_union, s_inp, wave, lane);
        __syncthreads();
        stage3s<3, DW>(0, Wb, Wbn, fW, bb, rho, s_union, qp, wave, lane);
        __syncthreads();
        stage2s<2, DW>(3, Wa, Wan, fW, ba, s_union, s_inp, wave, lane);
        __syncthreads();
        stage3s<2, DW>(3, Wb, Wbn, fW, bb, rho, s_union, qp, wave, lane);
        __syncthreads();
    }

    if (tid < 16) {
        out[b0 + tid] = s_q[tid] + ldf(rb1, 0, fW);
        out[Btot + b0 + tid] = s_q[16 + tid] + ldf(rb2, 0, fW);
    }
}

extern "C" void kernel_launch(void* const* d_in, const int* in_sizes, int n_in,
                              void* d_out, int out_size, void* d_ws, size_t ws_size,
                              hipStream_t stream) {
    int B = out_size / 2;  // 16384

    const void *obs = nullptr, *act = nullptr, *ag = nullptr, *g = nullptr;
    const void *mp_w = nullptr, *mp_b = nullptr;
    const void *w1 = nullptr, *b1 = nullptr, *w2 = nullptr, *b2 = nullptr;
    const void *w3 = nullptr, *b3 = nullptr, *w4 = nullptr, *b4 = nullptr;
    const void *rw1 = nullptr, *rb1 = nullptr, *rw2 = nullptr, *rb2 = nullptr;
    const int *eA = nullptr, *eB = nullptr, *pred = nullptr, *inc = nullptr;
    int c30 = 0, c256 = 0, c1 = 0, c40k = 0, c65k = 0, c20 = 0;
    for (int i = 0; i < n_in; ++i) {
        int sz = in_sizes[i];
        const void* p = d_in[i];
        if (sz == B * 85) obs = p;
        else if (sz == B * 30) { if (c30++ == 0) ag = p; else g = p; }
        else if (sz == 5888) mp_w = p;
        else if (sz == 128) mp_b = p;
        else if (sz == 40192) { if (c40k++ == 0) w1 = p; else w3 = p; }
        else if (sz == 65536 || sz == B * 4) {
            int c = c65k++;
            if (c == 0) act = p; else if (c == 1) w2 = p; else w4 = p;
        }
        else if (sz == 256) {
            int c = c256++;
            if (c == 0) b1 = p; else if (c == 1) b2 = p; else if (c == 2) b3 = p;
            else if (c == 3) b4 = p; else if (c == 4) rw1 = p; else rw2 = p;
        }
        else if (sz == 1) { if (c1++ == 0) rb1 = p; else rb2 = p; }
        else if (sz == 40) pred = (const int*)p;
        else if (sz == 20) {
            int c = c20++;
            if (c == 0) eA = (const int*)p;
            else if (c == 1) eB = (const int*)p;
            else inc = (const int*)p;
        }
    }
    if (!obs || !act || !ag || !g || !mp_w || !mp_b || !w1 || !b1 || !w2 || !b2 ||
        !w3 || !b3 || !w4 || !b4 || !rw1 || !rb1 || !rw2 || !rb2 || !eA || !eB ||
        !pred || !inc) {
        obs = d_in[0]; act = d_in[1]; ag = d_in[2]; g = d_in[3];
        mp_w = d_in[4]; mp_b = d_in[5]; w1 = d_in[6]; b1 = d_in[7];
        w2 = d_in[8]; b2 = d_in[9]; w3 = d_in[10]; b3 = d_in[11];
        w4 = d_in[12]; b4 = d_in[13]; rw1 = d_in[14]; rb1 = d_in[15];
        rw2 = d_in[16]; rb2 = d_in[17];
        eA = (const int*)d_in[18]; eB = (const int*)d_in[19];
        pred = (const int*)d_in[20]; inc = (const int*)d_in[21];
    }

    float* out = (float*)d_out;
    __bf16* wsW = (__bf16*)d_ws;
    bool use_ws = ws_size >= WS_BYTES + 8;
    int* flags = (int*)((char*)d_ws + WS_BYTES);
    int grid = B / 16;

    if (use_ws) {
        detect<<<1, 256, 0, stream>>>((const unsigned short*)obs,
                                      (const unsigned short*)w2, flags);
        swz<<<(WS_TOTAL + 255) / 256, 256, 0, stream>>>(mp_w, w1, w2, w3, w4, wsW, flags);
        gn_main<false><<<grid, 256, 0, stream>>>(
            obs, act, ag, g, mp_b, b1, b2, b3, b4, rw1, rb1, rw2, rb2,
            eA, eB, pred, inc, wsW, mp_w, w1, w2, w3, w4, flags, out, B);
    } else {
        gn_main<true><<<grid, 256, 0, stream>>>(
            obs, act, ag, g, mp_b, b1, b2, b3, b4, rw1, rb1, rw2, rb2,
            eA, eB, pred, inc, wsW, mp_w, w1, w2, w3, w4, flags, out, B);
    }
}

// Round 11
// 177.441 us; speedup vs baseline: 110.2408x; 1.2094x over previous
//
#include <hip/hip_runtime.h>
#include <hip/hip_bf16.h>

typedef __bf16 bf16x8 __attribute__((ext_vector_type(8)));
typedef __bf16 bf16x4 __attribute__((ext_vector_type(4)));
typedef float f32x4 __attribute__((ext_vector_type(4)));

#define MFMA(a, b, c) __builtin_amdgcn_mfma_f32_16x16x32_bf16(a, b, c, 0, 0, 0)

// ws layout (bf16 elem offsets) — weights in MFMA B-fragment order:
// frag[(nt*nKT + kt)*64 + lane][j] = W[kt*32 + (lane>>4)*8 + j][nt*16 + (lane&15)]
constexpr int MP_OFF = 0;
constexpr int W1_OFF = 8192;
constexpr int W2_OFF = 49152;
constexpr int W3_OFF = 114688;
constexpr int W4_OFF = 155648;
constexpr int WS_TOTAL = 221184;
constexpr size_t WS_BYTES = (size_t)WS_TOTAL * 2;

__device__ __forceinline__ float ldf(const void* p, int i, bool f32) {
    return f32 ? ((const float*)p)[i] : (float)(((const __bf16*)p)[i]);
}
__device__ __forceinline__ int geti(const int* p, int i, bool i64) {
    return p[i64 ? 2 * i : i];
}

// Wide dtype detector: fp32 misread as bf16 shows exponent-0xFF halfwords.
// flags must be pre-zeroed (hipMemsetAsync).
__global__ void detect(const unsigned short* __restrict__ uo,
                       const unsigned short* __restrict__ uw, int* __restrict__ flags) {
    int idx = blockIdx.x * 256 + threadIdx.x;
    if (idx < 8192) {
        if (((uo[idx] >> 7) & 0xFF) == 0xFF) atomicOr(&flags[0], 1);
        if (((uw[idx] >> 7) & 0xFF) == 0xFF) atomicOr(&flags[1], 1);
    }
}

// Read-side swizzle: thread <-> (padded-k, n) source-linear. Reads coalesced;
// scattered 2B writes drain without stalling. Pads write 0 (full coverage).
__global__ void swz(const void* __restrict__ mp, const void* __restrict__ w1,
                    const void* __restrict__ w2, const void* __restrict__ w3,
                    const void* __restrict__ w4, __bf16* __restrict__ ws,
                    const int* __restrict__ flags) {
    bool f32 = flags[1] != 0;
    int idx = blockIdx.x * blockDim.x + threadIdx.x;
    if (idx >= WS_TOTAL) return;
    const void* src;
    int base, local, nKT, nsh, style, K;
    if (idx < W1_OFF)      { src = mp; base = MP_OFF; local = idx;          nKT = 2; nsh = 7; style = 0; K = 46; }
    else if (idx < W2_OFF) { src = w1; base = W1_OFF; local = idx - W1_OFF; nKT = 5; nsh = 8; style = 1; K = 157; }
    else if (idx < W3_OFF) { src = w2; base = W2_OFF; local = idx - W2_OFF; nKT = 8; nsh = 8; style = 0; K = 256; }
    else if (idx < W4_OFF) { src = w3; base = W3_OFF; local = idx - W3_OFF; nKT = 5; nsh = 8; style = 1; K = 157; }
    else                   { src = w4; base = W4_OFF; local = idx - W4_OFF; nKT = 8; nsh = 8; style = 0; K = 256; }
    int N = 1 << nsh;
    int kp = local >> nsh, n = local & (N - 1);
    int ks = kp;
    bool ok = true;
    if (style == 1) { if (kp >= 32) ks = kp - 3; else if (kp >= 29) ok = false; }
    if (ks >= K) ok = false;
    float v = ok ? ldf(src, ks * N + n, f32) : 0.f;
    int dst = ((n >> 4) * nKT + (kp >> 5)) * 512 +
              (((((kp >> 3) & 3)) << 4) | (n & 15)) * 8 + (kp & 7);
    ws[base + dst] = (__bf16)v;
}

// Direct B-fragment gather fallback (ws too small). Same lane mapping as A-frag.
__device__ __forceinline__ bf16x8 gatherB(const void* W, bool f32, int style,
                                          int K, int N, int k0, int n, int q) {
    bf16x8 r;
#pragma unroll
    for (int j = 0; j < 8; ++j) {
        int k = k0 + q * 8 + j;
        bool ok = true;
        if (style == 1) { if (k >= 32) k -= 3; else if (k >= 29) ok = false; }
        if (k >= K) ok = false;
        float v = ok ? ldf(W, k * N + n, f32) : 0.f;
        r[j] = (__bf16)v;
    }
    return r;
}

// LDS (54,256 B -> alloc 54,272; 512-thr blocks, 8 waves; 2-3 blocks/CU):
//   s_union[0..12288)    : edge-A frags / h frags (aliased)
//   s_union[12288..14208): rowbuf 16 x 120 (dead after buildA<8,12>; s_q aliases head)
//   s_inp[12800]         : inp frags, 5 mt x 5 kt x 512
template <int PC, int PBASE>
__device__ __forceinline__ void buildA(__bf16* sA, const __bf16* rb, const int* s_esrc,
                                       const int* s_pid0, const int* s_pid1, int tid) {
    for (int i = tid; i < 16 * PC * 8; i += 512) {
        int r = i >> 3, oct = i & 7;
        int lb = r / PC, p = PBASE + r % PC;
        const __bf16* row = rb + lb * 120;
        bf16x8 v;
#pragma unroll
        for (int j = 0; j < 8; ++j) {
            int k = oct * 8 + j;
            __bf16 x = (__bf16)0.f;
            if (k < 10) x = row[k];
            else if (k < 14) x = row[85 + (k - 10)];
            else if (k < 16) x = row[89 + ((k == 14) ? s_pid0[p] : s_pid1[p])];
            else if (k < 31) x = row[10 + s_esrc[p] * 15 + (k - 16)];
            else if (k < 46) x = row[10 + (p >> 2) * 15 + (k - 31)];
            v[j] = x;
        }
        int t = (r >> 4) * 2 + (oct >> 2);
        int lanep = ((oct & 3) << 4) | (r & 15);
        *(bf16x8*)(sA + t * 512 + lanep * 8) = v;
    }
}

// stage1: A=edges, B=mp_w frags; 8 waves x 1 nt. Quad holds one (b,o) group.
template <int PC, int PBASE, bool DW>
__device__ __forceinline__ void stage1(const __bf16* Wf, const void* Wn, bool fW,
                                       const void* mp_b, const __bf16* sA,
                                       __bf16* s_inp, int wave, int lane) {
    int q = lane >> 4, c = lane & 15;
    int nt = wave;
    float mb = ldf(mp_b, nt * 16 + c, fW);
    f32x4 zero4 = {0.f, 0.f, 0.f, 0.f};
#pragma unroll
    for (int mtg = 0; mtg < PC / 4; ++mtg) {
        f32x4 acc[4];
#pragma unroll
        for (int m = 0; m < 4; ++m) acc[m] = zero4;
#pragma unroll
        for (int kt = 0; kt < 2; ++kt) {
            bf16x8 bw;
            if constexpr (DW) bw = gatherB(Wn, fW, 0, 46, 128, kt * 32, nt * 16 + c, q);
            else bw = *(const bf16x8*)(Wf + (nt * 2 + kt) * 512 + lane * 8);
#pragma unroll
            for (int m = 0; m < 4; ++m) {
                bf16x8 a = *(const bf16x8*)(sA + ((mtg * 4 + m) * 2 + kt) * 512 + lane * 8);
                acc[m] = MFMA(a, bw, acc[m]);
            }
        }
#pragma unroll
        for (int m = 0; m < 4; ++m) {
            int mt = mtg * 4 + m;
            float sum = 0.f;
#pragma unroll
            for (int rr = 0; rr < 4; ++rr) {
                float z = acc[m][rr] + mb;
                sum += (z > 0.f) ? z : 0.f;
            }
            int r0 = mt * 16 + q * 4;
            int lb = r0 / PC;
            int o = (PBASE + (r0 % PC)) >> 2;
            int rinp = lb * 5 + o;
            int kk = 32 + nt * 16 + c;
            s_inp[((rinp >> 4) * 5 + (kk >> 5)) * 512 +
                  ((((kk & 31) >> 3) << 4) + (rinp & 15)) * 8 + (kk & 7)] = (__bf16)sum;
        }
    }
}

// stage2 SWAPPED: D'[hcol][row] = MFMA(A=W1-frag, B=inp-frag); 8 waves x 2 ht.
// Epilogue: relu(+bias) -> one ds_write_b64 lands in exact A-frag layout for stage3.
template <int MTN, bool DW>
__device__ __forceinline__ void stage2s(int mbase, const __bf16* Wf, const void* Wn,
                                        bool fW, const void* Ba, __bf16* s_h,
                                        const __bf16* s_inp, int wave, int lane) {
    int q = lane >> 4, c = lane & 15;
    f32x4 zero4 = {0.f, 0.f, 0.f, 0.f};
    float bias_r[2][4];
#pragma unroll
    for (int n = 0; n < 2; ++n)
#pragma unroll
        for (int rg = 0; rg < 4; ++rg)
            bias_r[n][rg] = ldf(Ba, (wave * 2 + n) * 16 + q * 4 + rg, fW);
#pragma unroll
    for (int n = 0; n < 2; ++n) {
        int ht = wave * 2 + n;
        bf16x8 aw[5];
#pragma unroll
        for (int kt = 0; kt < 5; ++kt) {
            if constexpr (DW) aw[kt] = gatherB(Wn, fW, 1, 157, 256, kt * 32, ht * 16 + c, q);
            else aw[kt] = *(const bf16x8*)(Wf + (ht * 5 + kt) * 512 + lane * 8);
        }
        f32x4 acc[MTN];
#pragma unroll
        for (int m = 0; m < MTN; ++m) acc[m] = zero4;
#pragma unroll
        for (int kt = 0; kt < 5; ++kt) {
#pragma unroll
            for (int m = 0; m < MTN; ++m) {
                bf16x8 b = *(const bf16x8*)(s_inp + ((mbase + m) * 5 + kt) * 512 + lane * 8);
                acc[m] = MFMA(aw[kt], b, acc[m]);
            }
        }
#pragma unroll
        for (int m = 0; m < MTN; ++m) {
            bf16x4 hv;
#pragma unroll
            for (int rg = 0; rg < 4; ++rg) {
                float z = acc[m][rg] + bias_r[n][rg];
                hv[rg] = (__bf16)((z > 0.f) ? z : 0.f);
            }
            *(bf16x4*)(s_h + (m * 8 + (ht >> 1)) * 512 +
                       ((((ht & 1) * 2 + (q >> 1)) << 4) | c) * 8 + ((q & 1) << 2)) = hv;
        }
    }
}

// stage3 SWAPPED: D'[ncol][row] = MFMA(A=W2-frag, B=h-frag); 8 waves x 2 nt.
template <int MTN, bool DW>
__device__ __forceinline__ void stage3s(int mbase, const __bf16* Wf, const void* Wn,
                                        bool fW, const void* Bb, const void* Rh,
                                        const __bf16* s_h, float* s_qp, int wave, int lane) {
    int q = lane >> 4, c = lane & 15;
    f32x4 zero4 = {0.f, 0.f, 0.f, 0.f};
    float bias_r[2][4], rho_r[2][4];
#pragma unroll
    for (int n = 0; n < 2; ++n)
#pragma unroll
        for (int rg = 0; rg < 4; ++rg) {
            int ncol = (wave * 2 + n) * 16 + q * 4 + rg;
            bias_r[n][rg] = ldf(Bb, ncol, fW);
            rho_r[n][rg] = ldf(Rh, ncol, fW);
        }
    float rowsum[MTN];
#pragma unroll
    for (int m = 0; m < MTN; ++m) rowsum[m] = 0.f;
#pragma unroll
    for (int n = 0; n < 2; ++n) {
        int nt = wave * 2 + n;
        bf16x8 aw[8];
#pragma unroll
        for (int kt = 0; kt < 8; ++kt) {
            if constexpr (DW) aw[kt] = gatherB(Wn, fW, 0, 256, 256, kt * 32, nt * 16 + c, q);
            else aw[kt] = *(const bf16x8*)(Wf + (nt * 8 + kt) * 512 + lane * 8);
        }
        f32x4 acc[MTN];
#pragma unroll
        for (int m = 0; m < MTN; ++m) acc[m] = zero4;
#pragma unroll
        for (int kt = 0; kt < 8; ++kt) {
#pragma unroll
            for (int m = 0; m < MTN; ++m) {
                bf16x8 b = *(const bf16x8*)(s_h + (m * 8 + kt) * 512 + lane * 8);
                acc[m] = MFMA(aw[kt], b, acc[m]);
            }
        }
#pragma unroll
        for (int m = 0; m < MTN; ++m)
#pragma unroll
            for (int rg = 0; rg < 4; ++rg) {
                float z = acc[m][rg] + bias_r[n][rg];
                z = (z > 0.f) ? z : 0.f;
                rowsum[m] += z * rho_r[n][rg];
            }
    }
#pragma unroll
    for (int m = 0; m < MTN; ++m) {
        float v = rowsum[m];
        v += __shfl_xor(v, 16);
        v += __shfl_xor(v, 32);
        if (q == 0) {
            int r0 = (mbase + m) * 16 + c;  // rinp = b*5+o
            atomicAdd(&s_qp[r0 / 5], v);
        }
    }
}

template <bool DW>
__global__ __launch_bounds__(512, 4) void gn_main(
    const void* __restrict__ obs, const void* __restrict__ act,
    const void* __restrict__ ag, const void* __restrict__ g,
    const void* __restrict__ mp_b, const void* __restrict__ b1,
    const void* __restrict__ b2, const void* __restrict__ b3,
    const void* __restrict__ b4, const void* __restrict__ rw1,
    const void* __restrict__ rb1, const void* __restrict__ rw2,
    const void* __restrict__ rb2, const int* __restrict__ eA,
    const int* __restrict__ eB, const int* __restrict__ pred_ids,
    const int* __restrict__ incoming, const __bf16* __restrict__ wsW,
    const void* __restrict__ mp_w, const void* __restrict__ w1,
    const void* __restrict__ w2, const void* __restrict__ w3,
    const void* __restrict__ w4, const int* __restrict__ flags,
    float* __restrict__ out, int Btot) {
    __shared__ __align__(16) __bf16 s_union[14208];
    __shared__ __align__(16) __bf16 s_inp[12800];
    __shared__ int s_esrc[20], s_pid0[20], s_pid1[20];

    int tid = threadIdx.x, lane = tid & 63, wave = tid >> 6;
    __bf16* rb = s_union + 12288;
    float* s_q = (float*)(s_union + 12288);  // aliases rowbuf head (dead by stage3)
    int b0 = blockIdx.x * 16;

    // ---- dtype flags ----
    bool fI, fW;
    if constexpr (DW) {
        const unsigned short* uo = (const unsigned short*)obs;
        const unsigned short* uw = (const unsigned short*)w2;
        int d0 = 0, d1 = 0;
        for (int i = lane; i < 8192; i += 64) {
            if (((uo[i] >> 7) & 0xFF) == 0xFF) d0 = 1;
            if (((uw[i] >> 7) & 0xFF) == 0xFF) d1 = 1;
        }
        fI = __ballot(d0) != 0;
        fW = __ballot(d1) != 0;
    } else {
        fI = flags[0] != 0;
        fW = flags[1] != 0;
    }

    // ---- int width + src/dst disambiguation ----
    bool i64_i = (incoming[1] == 0);
    bool i64_p = (pred_ids[1] == 0);
    bool i64_e = (eA[9] == 0);
    const int* es = (geti(eA, 4, i64_e) == 1) ? eA : eB;

    if (tid < 20) {
        int e = geti(incoming, tid, i64_i);  // tid = o*4+j; edge p=tid has dst o=tid/4
        s_esrc[tid] = geti(es, e, i64_e);
        s_pid0[tid] = geti(pred_ids, 2 * e, i64_p);
        s_pid1[tid] = geti(pred_ids, 2 * e + 1, i64_p);
    }

    for (int i = tid; i < 16 * 120; i += 512) {
        int lb = i / 120, cidx = i % 120;
        int bg = b0 + lb;
        float v = 0.f;
        if (cidx < 85) v = ldf(obs, bg * 85 + cidx, fI);
        else if (cidx < 89) v = ldf(act, bg * 4 + (cidx - 85), fI);
        else if (cidx < 119) {
            int t = cidx - 89;
            v = ldf(g, bg * 30 + t, fI) - ldf(ag, bg * 30 + t, fI);
        }
        rb[i] = (__bf16)v;
    }
    __syncthreads();

    // inp kt=0 plane (k<32) as b128 blocks
    for (int i = tid; i < 80 * 4; i += 512) {
        int r = i >> 2, oct = i & 3;
        int lb = r / 5, o = r % 5;
        const __bf16* row = rb + lb * 120;
        bf16x8 v;
#pragma unroll
        for (int j = 0; j < 8; ++j) {
            int k = oct * 8 + j;
            __bf16 x = (__bf16)0.f;
            if (k < 4) x = row[85 + k];
            else if (k < 14) x = row[k - 4];
            else if (k < 29) x = row[10 + o * 15 + (k - 14)];
            v[j] = x;
        }
        *(bf16x8*)(s_inp + (r >> 4) * 2560 + ((oct << 4) | (r & 15)) * 8) = v;
    }
    buildA<12, 0>(s_union, rb, s_esrc, s_pid0, s_pid1, tid);
    __syncthreads();
    stage1<12, 0, DW>(wsW + MP_OFF, mp_w, fW, mp_b, s_union, s_inp, wave, lane);
    __syncthreads();
    buildA<8, 12>(s_union, rb, s_esrc, s_pid0, s_pid1, tid);
    __syncthreads();
    if (tid < 32) s_q[tid] = 0.f;  // rowbuf dead from here on
    stage1<8, 12, DW>(wsW + MP_OFF, mp_w, fW, mp_b, s_union, s_inp, wave, lane);
    __syncthreads();

    for (int P = 0; P < 2; ++P) {
        const __bf16* Wa = wsW + (P ? W3_OFF : W1_OFF);
        const __bf16* Wb = wsW + (P ? W4_OFF : W2_OFF);
        const void* Wan = P ? w3 : w1;
        const void* Wbn = P ? w4 : w2;
        const void* ba = P ? b3 : b1;
        const void* bb = P ? b4 : b2;
        const void* rho = P ? rw2 : rw1;
        float* qp = s_q + P * 16;
        stage2s<3, DW>(0, Wa, Wan, fW, ba, s_union, s_inp, wave, lane);
        __syncthreads();
        stage3s<3, DW>(0, Wb, Wbn, fW, bb, rho, s_union, qp, wave, lane);
        __syncthreads();
        stage2s<2, DW>(3, Wa, Wan, fW, ba, s_union, s_inp, wave, lane);
        __syncthreads();
        stage3s<2, DW>(3, Wb, Wbn, fW, bb, rho, s_union, qp, wave, lane);
        __syncthreads();
    }

    if (tid < 16) {
        out[b0 + tid] = s_q[tid] + ldf(rb1, 0, fW);
        out[Btot + b0 + tid] = s_q[16 + tid] + ldf(rb2, 0, fW);
    }
}

extern "C" void kernel_launch(void* const* d_in, const int* in_sizes, int n_in,
                              void* d_out, int out_size, void* d_ws, size_t ws_size,
                              hipStream_t stream) {
    int B = out_size / 2;  // 16384

    const void *obs = nullptr, *act = nullptr, *ag = nullptr, *g = nullptr;
    const void *mp_w = nullptr, *mp_b = nullptr;
    const void *w1 = nullptr, *b1 = nullptr, *w2 = nullptr, *b2 = nullptr;
    const void *w3 = nullptr, *b3 = nullptr, *w4 = nullptr, *b4 = nullptr;
    const void *rw1 = nullptr, *rb1 = nullptr, *rw2 = nullptr, *rb2 = nullptr;
    const int *eA = nullptr, *eB = nullptr, *pred = nullptr, *inc = nullptr;
    int c30 = 0, c256 = 0, c1 = 0, c40k = 0, c65k = 0, c20 = 0;
    for (int i = 0; i < n_in; ++i) {
        int sz = in_sizes[i];
        const void* p = d_in[i];
        if (sz == B * 85) obs = p;
        else if (sz == B * 30) { if (c30++ == 0) ag = p; else g = p; }
        else if (sz == 5888) mp_w = p;
        else if (sz == 128) mp_b = p;
        else if (sz == 40192) { if (c40k++ == 0) w1 = p; else w3 = p; }
        else if (sz == 65536 || sz == B * 4) {
            int c = c65k++;
            if (c == 0) act = p; else if (c == 1) w2 = p; else w4 = p;
        }
        else if (sz == 256) {
            int c = c256++;
            if (c == 0) b1 = p; else if (c == 1) b2 = p; else if (c == 2) b3 = p;
            else if (c == 3) b4 = p; else if (c == 4) rw1 = p; else rw2 = p;
        }
        else if (sz == 1) { if (c1++ == 0) rb1 = p; else rb2 = p; }
        else if (sz == 40) pred = (const int*)p;
        else if (sz == 20) {
            int c = c20++;
            if (c == 0) eA = (const int*)p;
            else if (c == 1) eB = (const int*)p;
            else inc = (const int*)p;
        }
    }
    if (!obs || !act || !ag || !g || !mp_w || !mp_b || !w1 || !b1 || !w2 || !b2 ||
        !w3 || !b3 || !w4 || !b4 || !rw1 || !rb1 || !rw2 || !rb2 || !eA || !eB ||
        !pred || !inc) {
        obs = d_in[0]; act = d_in[1]; ag = d_in[2]; g = d_in[3];
        mp_w = d_in[4]; mp_b = d_in[5]; w1 = d_in[6]; b1 = d_in[7];
        w2 = d_in[8]; b2 = d_in[9]; w3 = d_in[10]; b3 = d_in[11];
        w4 = d_in[12]; b4 = d_in[13]; rw1 = d_in[14]; rb1 = d_in[15];
        rw2 = d_in[16]; rb2 = d_in[17];
        eA = (const int*)d_in[18]; eB = (const int*)d_in[19];
        pred = (const int*)d_in[20]; inc = (const int*)d_in[21];
    }

    float* out = (float*)d_out;
    __bf16* wsW = (__bf16*)d_ws;
    bool use_ws = ws_size >= WS_BYTES + 8;
    int* flags = (int*)((char*)d_ws + WS_BYTES);
    int grid = B / 16;

    if (use_ws) {
        hipMemsetAsync(flags, 0, 8, stream);
        detect<<<32, 256, 0, stream>>>((const unsigned short*)obs,
                                       (const unsigned short*)w2, flags);
        swz<<<(WS_TOTAL + 255) / 256, 256, 0, stream>>>(mp_w, w1, w2, w3, w4, wsW, flags);
        gn_main<false><<<grid, 512, 0, stream>>>(
            obs, act, ag, g, mp_b, b1, b2, b3, b4, rw1, rb1, rw2, rb2,
            eA, eB, pred, inc, wsW, mp_w, w1, w2, w3, w4, flags, out, B);
    } else {
        gn_main<true><<<grid, 512, 0, stream>>>(
            obs, act, ag, g, mp_b, b1, b2, b3, b4, rw1, rb1, rw2, rb2,
            eA, eB, pred, inc, wsW, mp_w, w1, w2, w3, w4, flags, out, B);
    }
}